// Round 1
// baseline (125.401 us; speedup 1.0000x reference)
//
#include <hip/hip_runtime.h>

#define B_ 2
#define N_ 2048
#define M_ 2048
#define D_ 256
#define H_ 8
#define DH_ 32
#define SCALE 0.17677669529663689f  // 1/sqrt(32)

typedef __attribute__((ext_vector_type(8))) short short8;
typedef __attribute__((ext_vector_type(4))) float f32x4;

__device__ __forceinline__ unsigned short f2bf(float f) {
  unsigned int u = __float_as_uint(f);
  return (unsigned short)((u + 0x7fffu + ((u >> 16) & 1u)) >> 16);  // RNE
}

// ---------------- projection GEMM core ----------------
// One block: 16 rows x 256 cols of C = X[16x256] @ W[256x256] + bias.
// 256 threads; thread t: cols cg*4..cg*4+3 (cg=t&63), rows rg*4..rg*4+3 (rg=t>>6).
// MODE 0: bf16 out, [b*H+h][seq][32]    (q, k)
// MODE 1: bf16 out, [b*H+h][32][M]      (v, transposed for PV B-fragments)
// MODE 2: f32 out, plain [rows][256]    (final projection)
template <int MODE>
__device__ __forceinline__ void proj_core(
    const float* __restrict__ X, const float* __restrict__ W,
    const float* __restrict__ bias, void* __restrict__ outp,
    int row0, float (* __restrict__ xsT)[17]) {
  const int t = threadIdx.x;
  {  // stage 16x256 f32 tile, transposed -> xsT[k][r]
    const f32x4* xg = (const f32x4*)(X + (size_t)row0 * D_);
#pragma unroll
    for (int i = 0; i < 4; ++i) {
      int f = t + i * 256;
      int r = f >> 6;
      int k4 = (f & 63) << 2;
      f32x4 v = xg[f];
      xsT[k4 + 0][r] = v[0];
      xsT[k4 + 1][r] = v[1];
      xsT[k4 + 2][r] = v[2];
      xsT[k4 + 3][r] = v[3];
    }
  }
  __syncthreads();
  const int cg = t & 63;
  const int rg = t >> 6;
  float acc[4][4];
  {
    const f32x4 bb = *(const f32x4*)(bias + cg * 4);
#pragma unroll
    for (int i = 0; i < 4; ++i) {
      acc[i][0] = bb[0]; acc[i][1] = bb[1]; acc[i][2] = bb[2]; acc[i][3] = bb[3];
    }
  }
  const float* __restrict__ wp = W + cg * 4;
  for (int k = 0; k < 256; ++k) {
    f32x4 w = *(const f32x4*)(wp + (size_t)k * D_);
    const float* xc = &xsT[k][rg * 4];  // wave-uniform address -> LDS broadcast
#pragma unroll
    for (int i = 0; i < 4; ++i) {
      float xv = xc[i];
      acc[i][0] += xv * w[0];
      acc[i][1] += xv * w[1];
      acc[i][2] += xv * w[2];
      acc[i][3] += xv * w[3];
    }
  }

  if constexpr (MODE == 2) {
    float* of = (float*)outp;
#pragma unroll
    for (int i = 0; i < 4; ++i) {
      f32x4 v = {acc[i][0], acc[i][1], acc[i][2], acc[i][3]};
      *(f32x4*)(of + (size_t)(row0 + rg * 4 + i) * D_ + cg * 4) = v;
    }
  } else {
    unsigned short* ob_ = (unsigned short*)outp;
    const int b = row0 >> 11;                 // 2048 rows per batch
    const int sr0 = (row0 & (N_ - 1)) + rg * 4;
    const int hh = cg >> 3;                   // head = (cg*4)>>5
    const int d0 = (cg << 2) & 31;            // dim within head
    if constexpr (MODE == 0) {
#pragma unroll
      for (int i = 0; i < 4; ++i) {
        unsigned int w0 = (unsigned int)f2bf(acc[i][0]) | ((unsigned int)f2bf(acc[i][1]) << 16);
        unsigned int w1 = (unsigned int)f2bf(acc[i][2]) | ((unsigned int)f2bf(acc[i][3]) << 16);
        size_t addr = (((size_t)b * H_ + hh) * N_ + (sr0 + i)) * DH_ + d0;
        *(uint2*)(ob_ + addr) = make_uint2(w0, w1);
      }
    } else {  // MODE 1: transposed v
#pragma unroll
      for (int j = 0; j < 4; ++j) {
        unsigned int w0 = (unsigned int)f2bf(acc[0][j]) | ((unsigned int)f2bf(acc[1][j]) << 16);
        unsigned int w1 = (unsigned int)f2bf(acc[2][j]) | ((unsigned int)f2bf(acc[3][j]) << 16);
        size_t addr = (((size_t)b * H_ + hh) * DH_ + (d0 + j)) * M_ + sr0;
        *(uint2*)(ob_ + addr) = make_uint2(w0, w1);
      }
    }
  }
}

__global__ __launch_bounds__(256) void proj3_kernel(
    const float* __restrict__ Xq, const float* __restrict__ Xk, const float* __restrict__ Xv,
    const float* __restrict__ Wq, const float* __restrict__ bq,
    const float* __restrict__ Wk, const float* __restrict__ bk,
    const float* __restrict__ Wv, const float* __restrict__ bv,
    unsigned short* __restrict__ qb, unsigned short* __restrict__ kb,
    unsigned short* __restrict__ vtb) {
  __shared__ float xsT[256][17];
  int row0 = blockIdx.x * 16;
  if (blockIdx.y == 0)      proj_core<0>(Xq, Wq, bq, qb, row0, xsT);
  else if (blockIdx.y == 1) proj_core<0>(Xk, Wk, bk, kb, row0, xsT);
  else                      proj_core<1>(Xv, Wv, bv, vtb, row0, xsT);
}

__global__ __launch_bounds__(256) void projo_kernel(
    const float* __restrict__ X, const float* __restrict__ W,
    const float* __restrict__ bias, float* __restrict__ out) {
  __shared__ float xsT[256][17];
  proj_core<2>(X, W, bias, out, blockIdx.x * 16, xsT);
}

// ---------------- flash attention ----------------
// grid = B*H * (N/64); block = 256 = 4 independent waves, 16 query rows each.
// Per 32-key chunk: 2 MFMA (QK^T), masked online softmax (16-lane shfl reduce),
// P -> bf16 via wave-private LDS (C-layout -> A-fragment reshape), 2 MFMA (PV).
__global__ __launch_bounds__(256) void attn_kernel(
    const unsigned short* __restrict__ qb, const unsigned short* __restrict__ kb,
    const unsigned short* __restrict__ vtb, const float* __restrict__ presence,
    float* __restrict__ ob) {
  __shared__ unsigned short plds[4][640];  // per wave: 16 rows x stride 40 ushorts
  const int tid = threadIdx.x;
  const int wv = tid >> 6;
  const int lane = tid & 63;
  const int lr = lane & 15;
  const int lg = lane >> 4;
  const int bh = blockIdx.x >> 5;  // N/64 = 32 tiles per (b,h)
  const int tile = blockIdx.x & 31;
  const int b = bh >> 3;
  const int h = bh & 7;
  const int n0 = tile * 64 + wv * 16;

  // Q A-fragment: row = lane&15, k = (lane>>4)*8 + j  (16B load)
  const short8 qf = *(const short8*)(qb + ((size_t)bh * N_ + n0 + lr) * DH_ + lg * 8);

  f32x4 o0 = {0.f, 0.f, 0.f, 0.f};
  f32x4 o1 = {0.f, 0.f, 0.f, 0.f};
  float mj[4] = {-1e30f, -1e30f, -1e30f, -1e30f};
  float lj[4] = {0.f, 0.f, 0.f, 0.f};

  const unsigned short* kbase = kb + (size_t)bh * M_ * DH_;
  const unsigned short* vbase = vtb + (size_t)bh * DH_ * M_;
  const float* pbase = presence + (size_t)b * M_;
  unsigned short* pl = plds[wv];

  for (int m = 0; m < M_; m += 32) {
    const short8 kf0 = *(const short8*)(kbase + (size_t)(m + lr) * DH_ + lg * 8);
    const short8 kf1 = *(const short8*)(kbase + (size_t)(m + 16 + lr) * DH_ + lg * 8);
    const f32x4 z = {0.f, 0.f, 0.f, 0.f};
    f32x4 s0 = __builtin_amdgcn_mfma_f32_16x16x32_bf16(qf, kf0, z, 0, 0, 0);
    f32x4 s1 = __builtin_amdgcn_mfma_f32_16x16x32_bf16(qf, kf1, z, 0, 0, 0);
    // C layout: col(key) = lane&15, row(q) = (lane>>4)*4 + j   [m89-verified]
    const float pr0 = pbase[m + lr];
    const float pr1 = pbase[m + 16 + lr];
#pragma unroll
    for (int j = 0; j < 4; ++j) {
      float a0 = (pr0 != 0.f) ? s0[j] * SCALE : -1e30f;
      float a1 = (pr1 != 0.f) ? s1[j] * SCALE : -1e30f;
      float cm = fmaxf(a0, a1);
      cm = fmaxf(cm, __shfl_xor(cm, 1, 16));
      cm = fmaxf(cm, __shfl_xor(cm, 2, 16));
      cm = fmaxf(cm, __shfl_xor(cm, 4, 16));
      cm = fmaxf(cm, __shfl_xor(cm, 8, 16));
      const float mn = fmaxf(mj[j], cm);
      const float corr = __expf(mj[j] - mn);
      const float p0 = pr0 * __expf(a0 - mn);  // pr multiply: exact 0 when masked
      const float p1 = pr1 * __expf(a1 - mn);
      float rs = p0 + p1;
      rs += __shfl_xor(rs, 1, 16);
      rs += __shfl_xor(rs, 2, 16);
      rs += __shfl_xor(rs, 4, 16);
      rs += __shfl_xor(rs, 8, 16);
      lj[j] = lj[j] * corr + rs;
      mj[j] = mn;
      o0[j] *= corr;
      o1[j] *= corr;
      const int r = lg * 4 + j;
      pl[r * 40 + lr] = f2bf(p0);
      pl[r * 40 + 16 + lr] = f2bf(p1);
    }
    // P A-fragment: row = lane&15, k = (lane>>4)*8 + j  (stride 40 -> 16B aligned,
    // bank-period-8 -> 2-way (free) ds_read_b128)
    const short8 pf = *(const short8*)(pl + lr * 40 + lg * 8);
    const short8 vf0 = *(const short8*)(vbase + (size_t)lr * M_ + m + lg * 8);
    const short8 vf1 = *(const short8*)(vbase + (size_t)(16 + lr) * M_ + m + lg * 8);
    o0 = __builtin_amdgcn_mfma_f32_16x16x32_bf16(pf, vf0, o0, 0, 0, 0);
    o1 = __builtin_amdgcn_mfma_f32_16x16x32_bf16(pf, vf1, o1, 0, 0, 0);
  }

  float* obase = ob + ((size_t)b * N_ + n0) * D_ + h * DH_;
#pragma unroll
  for (int j = 0; j < 4; ++j) {
    const int r = lg * 4 + j;
    const float inv = 1.f / lj[j];
    obase[(size_t)r * D_ + lr] = o0[j] * inv;
    obase[(size_t)r * D_ + 16 + lr] = o1[j] * inv;
  }
}

extern "C" void kernel_launch(void* const* d_in, const int* in_sizes, int n_in,
                              void* d_out, int out_size, void* d_ws, size_t ws_size,
                              hipStream_t stream) {
  (void)in_sizes; (void)n_in; (void)out_size; (void)ws_size;
  const float* queries  = (const float*)d_in[0];
  const float* keys     = (const float*)d_in[1];
  const float* values   = (const float*)d_in[2];
  const float* presence = (const float*)d_in[3];
  const float* Wq = (const float*)d_in[4];
  const float* bq = (const float*)d_in[5];
  const float* Wk = (const float*)d_in[6];
  const float* bk = (const float*)d_in[7];
  const float* Wv = (const float*)d_in[8];
  const float* bv = (const float*)d_in[9];
  const float* Wo = (const float*)d_in[10];
  const float* bo = (const float*)d_in[11];

  unsigned short* qb  = (unsigned short*)d_ws;                       // 2 MB
  unsigned short* kb  = qb + (size_t)B_ * H_ * N_ * DH_;             // 2 MB
  unsigned short* vtb = kb + (size_t)B_ * H_ * M_ * DH_;             // 2 MB
  float* obuf = (float*)(vtb + (size_t)B_ * H_ * DH_ * M_);          // 4 MB

  proj3_kernel<<<dim3(B_ * N_ / 16, 3), 256, 0, stream>>>(
      queries, keys, values, Wq, bq, Wk, bk, Wv, bv, qb, kb, vtb);
  attn_kernel<<<dim3(B_ * H_ * N_ / 64), 256, 0, stream>>>(qb, kb, vtb, presence, obuf);
  projo_kernel<<<dim3(B_ * N_ / 16), 256, 0, stream>>>(obuf, Wo, bo, (float*)d_out);
}

// Round 2
// 106.058 us; speedup vs baseline: 1.1824x; 1.1824x over previous
//
#include <hip/hip_runtime.h>

#define B_ 2
#define N_ 2048
#define M_ 2048
#define D_ 256
#define H_ 8
#define DH_ 32
// 1/sqrt(32) * log2(e): fold into q projection so attention works in exp2 domain
#define QSCALE (0.17677669529663689f * 1.4426950408889634f)

typedef __attribute__((ext_vector_type(8))) short short8;
typedef __attribute__((ext_vector_type(4))) float f32x4;

#if __has_builtin(__builtin_amdgcn_exp2f)
#define EXP2 __builtin_amdgcn_exp2f
#else
#define EXP2 exp2f
#endif

__device__ __forceinline__ unsigned short f2bf(float f) {
  unsigned int u = __float_as_uint(f);
  return (unsigned short)((u + 0x7fffu + ((u >> 16) & 1u)) >> 16);  // RNE
}

__device__ __forceinline__ unsigned int cvtpk_bf16(float lo, float hi) {
  unsigned int r;
  asm("v_cvt_pk_bf16_f32 %0, %1, %2" : "=v"(r) : "v"(lo), "v"(hi));
  return r;
}

// ---------------- projection GEMM core ----------------
// One block: 16 rows x 256 cols of C = X[16x256] @ W[256x256] + bias.
// MODE 0: bf16 out (scaled by oscale), [b*H+h][seq][32]    (q, k)
// MODE 1: bf16 out, [b*H+h][32][M]      (v, transposed for PV A-fragments)
// MODE 2: f32 out, plain [rows][256]    (final projection)
template <int MODE>
__device__ __forceinline__ void proj_core(
    const float* __restrict__ X, const float* __restrict__ W,
    const float* __restrict__ bias, void* __restrict__ outp,
    int row0, float oscale, float (* __restrict__ xsT)[17]) {
  const int t = threadIdx.x;
  {  // stage 16x256 f32 tile, transposed -> xsT[k][r]
    const f32x4* xg = (const f32x4*)(X + (size_t)row0 * D_);
#pragma unroll
    for (int i = 0; i < 4; ++i) {
      int f = t + i * 256;
      int r = f >> 6;
      int k4 = (f & 63) << 2;
      f32x4 v = xg[f];
      xsT[k4 + 0][r] = v[0];
      xsT[k4 + 1][r] = v[1];
      xsT[k4 + 2][r] = v[2];
      xsT[k4 + 3][r] = v[3];
    }
  }
  __syncthreads();
  const int cg = t & 63;
  const int rg = t >> 6;
  float acc[4][4];
  {
    const f32x4 bb = *(const f32x4*)(bias + cg * 4);
#pragma unroll
    for (int i = 0; i < 4; ++i) {
      acc[i][0] = bb[0]; acc[i][1] = bb[1]; acc[i][2] = bb[2]; acc[i][3] = bb[3];
    }
  }
  const float* __restrict__ wp = W + cg * 4;
  for (int k = 0; k < 256; ++k) {
    f32x4 w = *(const f32x4*)(wp + (size_t)k * D_);
    const float* xc = &xsT[k][rg * 4];  // wave-uniform address -> LDS broadcast
#pragma unroll
    for (int i = 0; i < 4; ++i) {
      float xv = xc[i];
      acc[i][0] += xv * w[0];
      acc[i][1] += xv * w[1];
      acc[i][2] += xv * w[2];
      acc[i][3] += xv * w[3];
    }
  }

  if constexpr (MODE == 2) {
    float* of = (float*)outp;
#pragma unroll
    for (int i = 0; i < 4; ++i) {
      f32x4 v = {acc[i][0], acc[i][1], acc[i][2], acc[i][3]};
      *(f32x4*)(of + (size_t)(row0 + rg * 4 + i) * D_ + cg * 4) = v;
    }
  } else {
#pragma unroll
    for (int i = 0; i < 4; ++i)
#pragma unroll
      for (int j = 0; j < 4; ++j) acc[i][j] *= oscale;
    unsigned short* ob_ = (unsigned short*)outp;
    const int b = row0 >> 11;                 // 2048 rows per batch
    const int sr0 = (row0 & (N_ - 1)) + rg * 4;
    const int hh = cg >> 3;                   // head = (cg*4)>>5
    const int d0 = (cg << 2) & 31;            // dim within head
    if constexpr (MODE == 0) {
#pragma unroll
      for (int i = 0; i < 4; ++i) {
        unsigned int w0 = (unsigned int)f2bf(acc[i][0]) | ((unsigned int)f2bf(acc[i][1]) << 16);
        unsigned int w1 = (unsigned int)f2bf(acc[i][2]) | ((unsigned int)f2bf(acc[i][3]) << 16);
        size_t addr = (((size_t)b * H_ + hh) * N_ + (sr0 + i)) * DH_ + d0;
        *(uint2*)(ob_ + addr) = make_uint2(w0, w1);
      }
    } else {  // MODE 1: transposed v
#pragma unroll
      for (int j = 0; j < 4; ++j) {
        unsigned int w0 = (unsigned int)f2bf(acc[0][j]) | ((unsigned int)f2bf(acc[1][j]) << 16);
        unsigned int w1 = (unsigned int)f2bf(acc[2][j]) | ((unsigned int)f2bf(acc[3][j]) << 16);
        size_t addr = (((size_t)b * H_ + hh) * DH_ + (d0 + j)) * M_ + sr0;
        *(uint2*)(ob_ + addr) = make_uint2(w0, w1);
      }
    }
  }
}

__global__ __launch_bounds__(256) void proj3_kernel(
    const float* __restrict__ Xq, const float* __restrict__ Xk, const float* __restrict__ Xv,
    const float* __restrict__ Wq, const float* __restrict__ bq,
    const float* __restrict__ Wk, const float* __restrict__ bk,
    const float* __restrict__ Wv, const float* __restrict__ bv,
    unsigned short* __restrict__ qb, unsigned short* __restrict__ kb,
    unsigned short* __restrict__ vtb) {
  __shared__ float xsT[256][17];
  int row0 = blockIdx.x * 16;
  if (blockIdx.y == 0)      proj_core<0>(Xq, Wq, bq, qb, row0, QSCALE, xsT);
  else if (blockIdx.y == 1) proj_core<0>(Xk, Wk, bk, kb, row0, 1.0f, xsT);
  else                      proj_core<1>(Xv, Wv, bv, vtb, row0, 1.0f, xsT);
}

__global__ __launch_bounds__(256) void projo_kernel(
    const float* __restrict__ X, const float* __restrict__ W,
    const float* __restrict__ bias, float* __restrict__ out) {
  __shared__ float xsT[256][17];
  proj_core<2>(X, W, bias, out, blockIdx.x * 16, 1.0f, xsT);
}

// ---------------- flash attention (swapped-operand, in-register softmax) ----
// grid = B*H * (N/64); block = 256 = 4 independent waves, 16 query rows each.
// Per 64-key chunk: 4 MFMA S^T = mfma(K,Q) -> lane holds 16 scores of ONE query
// (col=lane&15=query, row=key [m89]); in-register online softmax (2 shuffles);
// P packed bf16 via v_cvt_pk -> wave-private LDS -> B-frag; O^T += mfma(V^T,P^T).
__global__ __launch_bounds__(256) void attn_kernel(
    const unsigned short* __restrict__ qb, const unsigned short* __restrict__ kb,
    const unsigned short* __restrict__ vtb, const float* __restrict__ presence,
    float* __restrict__ ob) {
  __shared__ unsigned short plds[4][16 * 72];  // 16 query rows x 64 keys, stride 144B
  const int tid = threadIdx.x;
  const int wv = tid >> 6;
  const int lane = tid & 63;
  const int lr = lane & 15;
  const int lg = lane >> 4;
  const int bh = blockIdx.x >> 5;  // 32 query tiles per (b,h)
  const int tile = blockIdx.x & 31;
  const int b = bh >> 3;
  const int h = bh & 7;
  const int n0 = tile * 64 + wv * 16;

  // Q as B-fragment of S^T = K·Q^T: col=query=lane&15, k=d=(lane>>4)*8+j
  const short8 qf = *(const short8*)(qb + ((size_t)bh * N_ + n0 + lr) * DH_ + lg * 8);

  const unsigned short* kbase = kb + (size_t)bh * M_ * DH_ + (size_t)lr * DH_ + lg * 8;
  const unsigned short* vbase = vtb + (size_t)bh * DH_ * M_ + (size_t)lr * M_ + lg * 8;
  const float* pbase = presence + (size_t)b * M_ + lg * 4;
  unsigned short* plw = plds[wv] + lr * 72;

  f32x4 o0 = {0.f, 0.f, 0.f, 0.f};  // O^T dims lg*4+j   for query lr
  f32x4 o1 = {0.f, 0.f, 0.f, 0.f};  // O^T dims 16+lg*4+j
  float mj = -1e30f, lj = 0.f;

  short8 kf[2][4], vf[2][4];
  f32x4 pv[2][4];

#define ALOAD(bb, mm) do {                                                   \
    _Pragma("unroll") for (int t_ = 0; t_ < 4; ++t_)                         \
      kf[bb][t_] = *(const short8*)(kbase + (size_t)((mm) + t_ * 16) * DH_); \
    vf[bb][0] = *(const short8*)(vbase + (mm));                              \
    vf[bb][1] = *(const short8*)(vbase + (mm) + 32);                         \
    vf[bb][2] = *(const short8*)(vbase + 16 * M_ + (mm));                    \
    vf[bb][3] = *(const short8*)(vbase + 16 * M_ + (mm) + 32);               \
    _Pragma("unroll") for (int t_ = 0; t_ < 4; ++t_)                         \
      pv[bb][t_] = *(const f32x4*)(pbase + (mm) + t_ * 16);                  \
  } while (0)

  ALOAD(0, 0);

  for (int m = 0; m < M_; m += 128) {
#pragma unroll
    for (int hf = 0; hf < 2; ++hf) {
      const int mm = m + hf * 64;
      const int nxt = mm + 64;
      if (nxt < M_) ALOAD(hf ^ 1, nxt);  // prefetch next chunk into other buffer

      // S^T: 4 MFMAs, keys mm+t*16+lg*4+j, query lr
      const f32x4 z = {0.f, 0.f, 0.f, 0.f};
      f32x4 s[4];
#pragma unroll
      for (int t = 0; t < 4; ++t)
        s[t] = __builtin_amdgcn_mfma_f32_16x16x32_bf16(kf[hf][t], qf, z, 0, 0, 0);
      // additive presence mask (exact 0 / -1e30); scores already in exp2 domain
#pragma unroll
      for (int t = 0; t < 4; ++t) s[t] += (pv[hf][t] - 1.f) * 1e30f;

      float cm = -1e30f;
#pragma unroll
      for (int t = 0; t < 4; ++t)
#pragma unroll
        for (int j = 0; j < 4; ++j) cm = fmaxf(cm, s[t][j]);
      cm = fmaxf(cm, __shfl_xor(cm, 16));
      cm = fmaxf(cm, __shfl_xor(cm, 32));
      const float mn = fmaxf(mj, cm);
      const float corr = EXP2(mj - mn);
      mj = mn;

      float rs = 0.f;
#pragma unroll
      for (int t = 0; t < 4; ++t) {
#pragma unroll
        for (int j = 0; j < 4; ++j) s[t][j] = EXP2(s[t][j] - mn);
        rs += (s[t][0] + s[t][1]) + (s[t][2] + s[t][3]);
      }
      rs += __shfl_xor(rs, 16);
      rs += __shfl_xor(rs, 32);
      lj = lj * corr + rs;
      o0 *= corr;
      o1 *= corr;

      // pack P -> bf16, write [query=lr][key]: key = t*16 + lg*4 + {0..3}
#pragma unroll
      for (int t = 0; t < 4; ++t) {
        uint2 w;
        w.x = cvtpk_bf16(s[t][0], s[t][1]);
        w.y = cvtpk_bf16(s[t][2], s[t][3]);
        *(uint2*)(plw + t * 16 + lg * 4) = w;
      }
      // P^T B-frag: col=query=lr, k=key = hh*32 + lg*8 + j
      const short8 pf0 = *(const short8*)(plw + lg * 8);
      const short8 pf1 = *(const short8*)(plw + 32 + lg * 8);
      o0 = __builtin_amdgcn_mfma_f32_16x16x32_bf16(vf[hf][0], pf0, o0, 0, 0, 0);
      o0 = __builtin_amdgcn_mfma_f32_16x16x32_bf16(vf[hf][1], pf1, o0, 0, 0, 0);
      o1 = __builtin_amdgcn_mfma_f32_16x16x32_bf16(vf[hf][2], pf0, o1, 0, 0, 0);
      o1 = __builtin_amdgcn_mfma_f32_16x16x32_bf16(vf[hf][3], pf1, o1, 0, 0, 0);
    }
  }
#undef ALOAD

  const float inv = 1.f / lj;
  float* obase = ob + ((size_t)b * N_ + n0 + lr) * D_ + h * DH_;
  f32x4 r0 = o0 * inv;
  f32x4 r1 = o1 * inv;
  *(f32x4*)(obase + lg * 4) = r0;
  *(f32x4*)(obase + 16 + lg * 4) = r1;
}

extern "C" void kernel_launch(void* const* d_in, const int* in_sizes, int n_in,
                              void* d_out, int out_size, void* d_ws, size_t ws_size,
                              hipStream_t stream) {
  (void)in_sizes; (void)n_in; (void)out_size; (void)ws_size;
  const float* queries  = (const float*)d_in[0];
  const float* keys     = (const float*)d_in[1];
  const float* values   = (const float*)d_in[2];
  const float* presence = (const float*)d_in[3];
  const float* Wq = (const float*)d_in[4];
  const float* bq = (const float*)d_in[5];
  const float* Wk = (const float*)d_in[6];
  const float* bk = (const float*)d_in[7];
  const float* Wv = (const float*)d_in[8];
  const float* bv = (const float*)d_in[9];
  const float* Wo = (const float*)d_in[10];
  const float* bo = (const float*)d_in[11];

  unsigned short* qb  = (unsigned short*)d_ws;                       // 2 MB
  unsigned short* kb  = qb + (size_t)B_ * H_ * N_ * DH_;             // 2 MB
  unsigned short* vtb = kb + (size_t)B_ * H_ * M_ * DH_;             // 2 MB
  float* obuf = (float*)(vtb + (size_t)B_ * H_ * DH_ * M_);          // 4 MB

  proj3_kernel<<<dim3(B_ * N_ / 16, 3), 256, 0, stream>>>(
      queries, keys, values, Wq, bq, Wk, bk, Wv, bv, qb, kb, vtb);
  attn_kernel<<<dim3(B_ * H_ * N_ / 64), 256, 0, stream>>>(qb, kb, vtb, presence, obuf);
  projo_kernel<<<dim3(B_ * N_ / 16), 256, 0, stream>>>(obuf, Wo, bo, (float*)d_out);
}

// Round 3
// 89.288 us; speedup vs baseline: 1.4045x; 1.1878x over previous
//
#include <hip/hip_runtime.h>

#define B_ 2
#define N_ 2048
#define M_ 2048
#define D_ 256
#define H_ 8
#define DH_ 32
// 1/sqrt(32) * log2(e): fold into q projection; attention works in exp2 domain
#define QSCALE (0.17677669529663689f * 1.4426950408889634f)

typedef __attribute__((ext_vector_type(8))) short short8;
typedef __attribute__((ext_vector_type(4))) float f32x4;
typedef unsigned short u16;
typedef unsigned int u32;

#if __has_builtin(__builtin_amdgcn_exp2f)
#define EXP2 __builtin_amdgcn_exp2f
#else
#define EXP2 exp2f
#endif

__device__ __forceinline__ u16 f2bf(float f) {
  u32 u = __float_as_uint(f);
  return (u16)((u + 0x7fffu + ((u >> 16) & 1u)) >> 16);  // RNE
}
__device__ __forceinline__ u32 cvtpk_bf16(float lo, float hi) {
  u32 r;
  asm("v_cvt_pk_bf16_f32 %0, %1, %2" : "=v"(r) : "v"(lo), "v"(hi));
  return r;
}

union u4s8 { uint4 u; short8 s; };

// ---------- K0: convert X (f32 -> bf16 row-major) and W (f32 -> bf16 transposed) ----------
__global__ __launch_bounds__(256) void conv_kernel(
    const float* __restrict__ Xq, const float* __restrict__ Xk, const float* __restrict__ Xv,
    const float* __restrict__ Wq, const float* __restrict__ Wk,
    const float* __restrict__ Wv, const float* __restrict__ Wo,
    u16* __restrict__ xqb, u16* __restrict__ xkb, u16* __restrict__ xvb,
    u16* __restrict__ wTq, u16* __restrict__ wTk, u16* __restrict__ wTv,
    u16* __restrict__ wTo) {
  __shared__ u16 sh[64][72];
  int blk = blockIdx.x;
  if (blk < 1536) {  // X convert: 512 blocks per input, 8 elems/thread
    const int wi = blk >> 9;
    const float* src = wi == 0 ? Xq : (wi == 1 ? Xk : Xv);
    u16* dst = wi == 0 ? xqb : (wi == 1 ? xkb : xvb);
    const size_t off = (((size_t)(blk & 511)) * 256 + threadIdx.x) * 8;
    const f32x4 a = *(const f32x4*)(src + off);
    const f32x4 b = *(const f32x4*)(src + off + 4);
    uint4 o;
    o.x = cvtpk_bf16(a[0], a[1]);
    o.y = cvtpk_bf16(a[2], a[3]);
    o.z = cvtpk_bf16(b[0], b[1]);
    o.w = cvtpk_bf16(b[2], b[3]);
    *(uint4*)(dst + off) = o;
  } else {  // W transpose-convert: 16 blocks of 64x64 tile per matrix
    blk -= 1536;
    const int mi = blk >> 4, tile = blk & 15;
    const float* Ws = mi == 0 ? Wq : mi == 1 ? Wk : mi == 2 ? Wv : Wo;
    u16* Wd = mi == 0 ? wTq : mi == 1 ? wTk : mi == 2 ? wTv : wTo;
    const int r0 = (tile >> 2) * 64, c0 = (tile & 3) * 64;
    const int r = threadIdx.x & 63, qt = threadIdx.x >> 6;
    const float* sp = Ws + (size_t)(r0 + r) * D_ + c0 + qt * 16;
    u32 w[8];
#pragma unroll
    for (int i = 0; i < 4; ++i) {
      f32x4 v = *(const f32x4*)(sp + i * 4);
      w[i * 2 + 0] = cvtpk_bf16(v[0], v[1]);
      w[i * 2 + 1] = cvtpk_bf16(v[2], v[3]);
    }
    *(uint4*)(&sh[r][qt * 16]) = *(uint4*)&w[0];
    *(uint4*)(&sh[r][qt * 16 + 8]) = *(uint4*)&w[4];
    __syncthreads();
    const int cc = threadIdx.x & 63;
    u32 t2[8];
#pragma unroll
    for (int i = 0; i < 8; ++i) {
      u32 lo = sh[qt * 16 + 2 * i][cc];
      u32 hi = sh[qt * 16 + 2 * i + 1][cc];
      t2[i] = lo | (hi << 16);
    }
    u16* op = Wd + (size_t)(c0 + cc) * D_ + r0 + qt * 16;
    *(uint4*)op = *(uint4*)&t2[0];
    *(uint4*)(op + 8) = *(uint4*)&t2[4];
  }
}

// ---------- K1: q/k/v projections via bf16 MFMA ----------
// p=0 (q), p=1 (k): direct form, wave = 16 rows x 64 cols -> [bh][n][32]
// p=2 (v): swapped form, wave = 16 out-channels x 64 rows -> vtb [bh][32][M]
__global__ __launch_bounds__(256) void qkvproj_kernel(
    const u16* __restrict__ xqb, const u16* __restrict__ xkb, const u16* __restrict__ xvb,
    const u16* __restrict__ wTq, const u16* __restrict__ wTk, const u16* __restrict__ wTv,
    const float* __restrict__ bq, const float* __restrict__ bk, const float* __restrict__ bv,
    u16* __restrict__ qb, u16* __restrict__ kb, u16* __restrict__ vtb) {
  const int p = blockIdx.y;
  const int task = blockIdx.x * 4 + (threadIdx.x >> 6);
  const int lane = threadIdx.x & 63, lr = lane & 15, lg = lane >> 4;
  const u16* xb = p == 0 ? xqb : (p == 1 ? xkb : xvb);
  const u16* wT = p == 0 ? wTq : (p == 1 ? wTk : wTv);
  const float* bias = p == 0 ? bq : (p == 1 ? bk : bv);
  const f32x4 zz = {0.f, 0.f, 0.f, 0.f};
  f32x4 acc[4] = {zz, zz, zz, zz};

  if (p < 2) {
    const int n0 = (task >> 2) * 16, c0 = (task & 3) * 64;
    const u16* ap = xb + ((size_t)n0 + lr) * D_ + lg * 8;
    const u16* bp = wT + ((size_t)c0 + lr) * D_ + lg * 8;
#pragma unroll
    for (int ks = 0; ks < 8; ++ks) {
      const short8 a = *(const short8*)(ap + ks * 32);
#pragma unroll
      for (int cg = 0; cg < 4; ++cg) {
        const short8 b = *(const short8*)(bp + (size_t)cg * 16 * D_ + ks * 32);
        acc[cg] = __builtin_amdgcn_mfma_f32_16x16x32_bf16(a, b, acc[cg], 0, 0, 0);
      }
    }
    u16* ob = p == 0 ? qb : kb;
    const float sc = p == 0 ? QSCALE : 1.0f;
    const int bidx = n0 >> 11;
    const int nn = (n0 & (N_ - 1)) + lg * 4;
#pragma unroll
    for (int cg = 0; cg < 4; ++cg) {
      const int c = c0 + cg * 16 + lr;
      const float bb = bias[c];
      const int hh = c >> 5, dd = c & 31;
      u16* op = ob + (((size_t)(bidx * H_ + hh)) * N_ + nn) * DH_ + dd;
#pragma unroll
      for (int j = 0; j < 4; ++j) op[j * DH_] = f2bf((acc[cg][j] + bb) * sc);
    }
  } else {
    const int c0 = (task & 15) * 16, n0 = (task >> 4) * 64;
    const u16* ap = wT + ((size_t)c0 + lr) * D_ + lg * 8;
    const u16* bp = xb + ((size_t)n0 + lr) * D_ + lg * 8;
#pragma unroll
    for (int ks = 0; ks < 8; ++ks) {
      const short8 a = *(const short8*)(ap + ks * 32);
#pragma unroll
      for (int ng = 0; ng < 4; ++ng) {
        const short8 b = *(const short8*)(bp + (size_t)ng * 16 * D_ + ks * 32);
        acc[ng] = __builtin_amdgcn_mfma_f32_16x16x32_bf16(a, b, acc[ng], 0, 0, 0);
      }
    }
    const int bidx = n0 >> 11, m0r = n0 & (M_ - 1);
    const int hh = c0 >> 5;
    const f32x4 bias4 = *(const f32x4*)(bias + c0 + lg * 4);
#pragma unroll
    for (int ng = 0; ng < 4; ++ng) {
#pragma unroll
      for (int j = 0; j < 4; ++j) {
        const int dd = (c0 & 31) + lg * 4 + j;
        vtb[(((size_t)(bidx * H_ + hh)) * DH_ + dd) * M_ + m0r + ng * 16 + lr] =
            f2bf(acc[ng][j] + bias4[j]);
      }
    }
  }
}

// ---------- K2: flash attention, no-max (fixed max 0), key-split 2 ----------
// grid = 2 splits x 16 bh x 32 qtiles; block = 4 waves, 16 query rows each.
// Per 64-key chunk: 4 MFMA S^T=mfma(K,Q) (lane: query=lr, key=t*16+lg*4+j);
// additive presence mask; exp2 (no max, no rescale); pack bf16 -> swizzled
// LDS [16q][64k] (16B-slot XOR by lr&7, conflict-free both sides);
// O = mfma(P, V^T) -> query-major; write unnormalized f32 partials + l.
__global__ __launch_bounds__(256, 4) void attn_kernel(
    const u16* __restrict__ qb, const u16* __restrict__ kb,
    const u16* __restrict__ vtb, const float* __restrict__ presence,
    float* __restrict__ opart, float* __restrict__ lpart) {
  __shared__ u16 plds[4][1024];  // per wave: 16 rows x 64 keys, 128B rows, swizzled
  const int tid = threadIdx.x;
  const int wv = tid >> 6, lane = tid & 63;
  const int lr = lane & 15, lg = lane >> 4;
  const int s = blockIdx.x >> 9;
  const int bh = (blockIdx.x >> 5) & 15;
  const int tile = blockIdx.x & 31;
  const int b = bh >> 3, h = bh & 7;
  const int n0 = tile * 64 + wv * 16;
  const int m0 = s * (M_ / 2);

  // Q as B-frag of S^T: col=query=lr, k=d=lg*8+j
  const short8 qf = *(const short8*)(qb + ((size_t)bh * N_ + n0 + lr) * DH_ + lg * 8);
  const u16* kbase = kb + ((size_t)bh * M_ + m0 + lr) * DH_ + lg * 8;
  const u16* vbase = vtb + ((size_t)bh * DH_ + lr) * M_ + m0 + lg * 8;
  const float* pbase = presence + (size_t)b * M_ + m0 + lg * 4;
  u16* pl = plds[wv] + lr * 64;  // 128B row base

  const f32x4 zz = {0.f, 0.f, 0.f, 0.f};
  f32x4 o0 = zz, o1 = zz, racc = zz;
  const int sw = lr & 7;

  for (int i = 0; i < 16; ++i) {
    const int mm = i * 64;
    short8 kf[4];
#pragma unroll
    for (int t = 0; t < 4; ++t)
      kf[t] = *(const short8*)(kbase + (size_t)(mm + t * 16) * DH_);
    const short8 vf0 = *(const short8*)(vbase + mm);
    const short8 vf1 = *(const short8*)(vbase + mm + 32);
    const short8 vf2 = *(const short8*)(vbase + (size_t)16 * M_ + mm);
    const short8 vf3 = *(const short8*)(vbase + (size_t)16 * M_ + mm + 32);
    f32x4 pv[4];
#pragma unroll
    for (int t = 0; t < 4; ++t) pv[t] = *(const f32x4*)(pbase + mm + t * 16);

    f32x4 s4[4];
#pragma unroll
    for (int t = 0; t < 4; ++t)
      s4[t] = __builtin_amdgcn_mfma_f32_16x16x32_bf16(kf[t], qf, zz, 0, 0, 0);
#pragma unroll
    for (int t = 0; t < 4; ++t) {
      s4[t] += (pv[t] - 1.f) * 1e30f;  // exact 0 when present, -1e30 when masked
#pragma unroll
      for (int j = 0; j < 4; ++j) s4[t][j] = EXP2(s4[t][j]);
      racc += s4[t];
      const u32 wx = cvtpk_bf16(s4[t][0], s4[t][1]);
      const u32 wy = cvtpk_bf16(s4[t][2], s4[t][3]);
      const int slot = (2 * t + (lg >> 1)) ^ sw;
      *(uint2*)(pl + slot * 8 + (lg & 1) * 4) = make_uint2(wx, wy);
    }
    const short8 pf0 = *(const short8*)(pl + (lg ^ sw) * 8);
    const short8 pf1 = *(const short8*)(pl + ((4 + lg) ^ sw) * 8);
    o0 = __builtin_amdgcn_mfma_f32_16x16x32_bf16(pf0, vf0, o0, 0, 0, 0);
    o0 = __builtin_amdgcn_mfma_f32_16x16x32_bf16(pf1, vf1, o0, 0, 0, 0);
    o1 = __builtin_amdgcn_mfma_f32_16x16x32_bf16(pf0, vf2, o1, 0, 0, 0);
    o1 = __builtin_amdgcn_mfma_f32_16x16x32_bf16(pf1, vf3, o1, 0, 0, 0);
  }

  float l = (racc[0] + racc[1]) + (racc[2] + racc[3]);
  l += __shfl_xor(l, 16);
  l += __shfl_xor(l, 32);
  if (lg == 0) lpart[((size_t)s * (B_ * N_) + b * N_ + n0 + lr) * H_ + h] = l;

  float* ob = opart + ((size_t)s * (B_ * N_) + (size_t)b * N_ + n0) * D_ + h * DH_;
#pragma unroll
  for (int j = 0; j < 4; ++j) {
    const int q = lg * 4 + j;
    ob[(size_t)q * D_ + lr] = o0[j];
    ob[(size_t)q * D_ + 16 + lr] = o1[j];
  }
}

// ---------- K3: output projection (combine partials, normalize, bf16 MFMA) ----------
__global__ __launch_bounds__(256) void projo_kernel(
    const float* __restrict__ opart, const float* __restrict__ lpart,
    const u16* __restrict__ wTo, const float* __restrict__ bo,
    float* __restrict__ out) {
  const int task = blockIdx.x * 4 + (threadIdx.x >> 6);
  const int lane = threadIdx.x & 63, lr = lane & 15, lg = lane >> 4;
  const int n0 = (task >> 2) * 16, c0 = (task & 3) * 64;
  const float* o0p = opart + ((size_t)n0 + lr) * D_ + lg * 8;
  const float* o1p = o0p + (size_t)(B_ * N_) * D_;
  const float* l0 = lpart + ((size_t)n0 + lr) * H_;
  const float* l1 = l0 + (size_t)(B_ * N_) * H_;
  float il[8];
#pragma unroll
  for (int hh = 0; hh < 8; ++hh) il[hh] = 1.0f / (l0[hh] + l1[hh]);

  const u16* bp = wTo + ((size_t)c0 + lr) * D_ + lg * 8;
  const f32x4 zz = {0.f, 0.f, 0.f, 0.f};
  f32x4 acc[4] = {zz, zz, zz, zz};
#pragma unroll
  for (int ks = 0; ks < 8; ++ks) {
    f32x4 xa = *(const f32x4*)(o0p + ks * 32) + *(const f32x4*)(o1p + ks * 32);
    f32x4 xb = *(const f32x4*)(o0p + ks * 32 + 4) + *(const f32x4*)(o1p + ks * 32 + 4);
    const float sc = il[ks];  // head of channels ks*32+lg*8+j is ks
    xa *= sc;
    xb *= sc;
    u4s8 a;
    a.u.x = cvtpk_bf16(xa[0], xa[1]);
    a.u.y = cvtpk_bf16(xa[2], xa[3]);
    a.u.z = cvtpk_bf16(xb[0], xb[1]);
    a.u.w = cvtpk_bf16(xb[2], xb[3]);
#pragma unroll
    for (int cg = 0; cg < 4; ++cg) {
      const short8 b = *(const short8*)(bp + (size_t)cg * 16 * D_ + ks * 32);
      acc[cg] = __builtin_amdgcn_mfma_f32_16x16x32_bf16(a.s, b, acc[cg], 0, 0, 0);
    }
  }
#pragma unroll
  for (int cg = 0; cg < 4; ++cg) {
    const int c = c0 + cg * 16 + lr;
    const float bb = bo[c];
#pragma unroll
    for (int j = 0; j < 4; ++j)
      out[(size_t)(n0 + lg * 4 + j) * D_ + c] = acc[cg][j] + bb;
  }
}

extern "C" void kernel_launch(void* const* d_in, const int* in_sizes, int n_in,
                              void* d_out, int out_size, void* d_ws, size_t ws_size,
                              hipStream_t stream) {
  (void)in_sizes; (void)n_in; (void)out_size; (void)ws_size;
  const float* queries  = (const float*)d_in[0];
  const float* keys     = (const float*)d_in[1];
  const float* values   = (const float*)d_in[2];
  const float* presence = (const float*)d_in[3];
  const float* Wq = (const float*)d_in[4];
  const float* bq = (const float*)d_in[5];
  const float* Wk = (const float*)d_in[6];
  const float* bk = (const float*)d_in[7];
  const float* Wv = (const float*)d_in[8];
  const float* bv = (const float*)d_in[9];
  const float* Wo = (const float*)d_in[10];
  const float* bo = (const float*)d_in[11];

  // ws layout (14.75 MB): wT x4 | qb | kb | vtb | {xqb,xkb,xvb overlapped by opart}+lpart
  u16* wTq = (u16*)d_ws;
  u16* wTk = wTq + 65536;
  u16* wTv = wTk + 65536;
  u16* wTo = wTv + 65536;
  u16* qb  = wTo + 65536;
  u16* kb  = qb + (size_t)B_ * H_ * N_ * DH_;
  u16* vtb = kb + (size_t)B_ * H_ * M_ * DH_;
  u16* xqb = vtb + (size_t)B_ * H_ * DH_ * M_;
  u16* xkb = xqb + (size_t)B_ * N_ * D_;
  u16* xvb = xkb + (size_t)B_ * M_ * D_;
  float* opart = (float*)xqb;  // reuses x-convert region after qkvproj consumed it
  float* lpart = opart + (size_t)2 * B_ * N_ * D_;

  conv_kernel<<<1600, 256, 0, stream>>>(queries, keys, values, Wq, Wk, Wv, Wo,
                                        xqb, xkb, xvb, wTq, wTk, wTv, wTo);
  qkvproj_kernel<<<dim3(256, 3), 256, 0, stream>>>(xqb, xkb, xvb, wTq, wTk, wTv,
                                                   bq, bk, bv, qb, kb, vtb);
  attn_kernel<<<1024, 256, 0, stream>>>(qb, kb, vtb, presence, opart, lpart);
  projo_kernel<<<256, 256, 0, stream>>>(opart, lpart, wTo, bo, (float*)d_out);
}

// Round 4
// 59.602 us; speedup vs baseline: 2.1040x; 1.4981x over previous
//
#include <hip/hip_runtime.h>

#define B_ 2
#define N_ 2048
#define M_ 2048
#define D_ 256
#define H_ 8
#define DH_ 32
// 1/sqrt(32) * log2(e): fold into q projection; attention works in exp2 domain
#define QSCALE (0.17677669529663689f * 1.4426950408889634f)

typedef __attribute__((ext_vector_type(8))) short short8;
typedef __attribute__((ext_vector_type(4))) float f32x4;
typedef unsigned short u16;
typedef unsigned int u32;

#if __has_builtin(__builtin_amdgcn_exp2f)
#define EXP2 __builtin_amdgcn_exp2f
#else
#define EXP2 exp2f
#endif

__device__ __forceinline__ u16 f2bf(float f) {
  u32 u = __float_as_uint(f);
  return (u16)((u + 0x7fffu + ((u >> 16) & 1u)) >> 16);  // RNE
}
__device__ __forceinline__ u32 cvtpk_bf16(float lo, float hi) {
  u32 r;
  asm("v_cvt_pk_bf16_f32 %0, %1, %2" : "=v"(r) : "v"(lo), "v"(hi));
  return r;
}
__device__ __forceinline__ void gload_lds16(const u16* g, u16* l) {
  __builtin_amdgcn_global_load_lds((const __attribute__((address_space(1))) void*)g,
                                   (__attribute__((address_space(3))) void*)l, 16, 0, 0);
}

union u4s8 { uint4 u; short8 s; };

// ---------- K0: convert X (f32 -> bf16 row-major) and W (f32 -> bf16 transposed) ----------
__global__ __launch_bounds__(256) void conv_kernel(
    const float* __restrict__ Xq, const float* __restrict__ Xk, const float* __restrict__ Xv,
    const float* __restrict__ Wq, const float* __restrict__ Wk,
    const float* __restrict__ Wv, const float* __restrict__ Wo,
    u16* __restrict__ xqb, u16* __restrict__ xkb, u16* __restrict__ xvb,
    u16* __restrict__ wTq, u16* __restrict__ wTk, u16* __restrict__ wTv,
    u16* __restrict__ wTo) {
  __shared__ u16 sh[64][72];
  int blk = blockIdx.x;
  if (blk < 1536) {  // X convert: 512 blocks per input, 8 elems/thread
    const int wi = blk >> 9;
    const float* src = wi == 0 ? Xq : (wi == 1 ? Xk : Xv);
    u16* dst = wi == 0 ? xqb : (wi == 1 ? xkb : xvb);
    const size_t off = (((size_t)(blk & 511)) * 256 + threadIdx.x) * 8;
    const f32x4 a = *(const f32x4*)(src + off);
    const f32x4 b = *(const f32x4*)(src + off + 4);
    uint4 o;
    o.x = cvtpk_bf16(a[0], a[1]);
    o.y = cvtpk_bf16(a[2], a[3]);
    o.z = cvtpk_bf16(b[0], b[1]);
    o.w = cvtpk_bf16(b[2], b[3]);
    *(uint4*)(dst + off) = o;
  } else {  // W transpose-convert: 16 blocks of 64x64 tile per matrix
    blk -= 1536;
    const int mi = blk >> 4, tile = blk & 15;
    const float* Ws = mi == 0 ? Wq : mi == 1 ? Wk : mi == 2 ? Wv : Wo;
    u16* Wd = mi == 0 ? wTq : mi == 1 ? wTk : mi == 2 ? wTv : wTo;
    const int r0 = (tile >> 2) * 64, c0 = (tile & 3) * 64;
    const int r = threadIdx.x & 63, qt = threadIdx.x >> 6;
    const float* sp = Ws + (size_t)(r0 + r) * D_ + c0 + qt * 16;
    u32 w[8];
#pragma unroll
    for (int i = 0; i < 4; ++i) {
      f32x4 v = *(const f32x4*)(sp + i * 4);
      w[i * 2 + 0] = cvtpk_bf16(v[0], v[1]);
      w[i * 2 + 1] = cvtpk_bf16(v[2], v[3]);
    }
    *(uint4*)(&sh[r][qt * 16]) = *(uint4*)&w[0];
    *(uint4*)(&sh[r][qt * 16 + 8]) = *(uint4*)&w[4];
    __syncthreads();
    const int cc = threadIdx.x & 63;
    u32 t2[8];
#pragma unroll
    for (int i = 0; i < 8; ++i) {
      u32 lo = sh[qt * 16 + 2 * i][cc];
      u32 hi = sh[qt * 16 + 2 * i + 1][cc];
      t2[i] = lo | (hi << 16);
    }
    u16* op = Wd + (size_t)(c0 + cc) * D_ + r0 + qt * 16;
    *(uint4*)op = *(uint4*)&t2[0];
    *(uint4*)(op + 8) = *(uint4*)&t2[4];
  }
}

// ---------- K1: q/k/v projections via bf16 MFMA ----------
__global__ __launch_bounds__(256) void qkvproj_kernel(
    const u16* __restrict__ xqb, const u16* __restrict__ xkb, const u16* __restrict__ xvb,
    const u16* __restrict__ wTq, const u16* __restrict__ wTk, const u16* __restrict__ wTv,
    const float* __restrict__ bq, const float* __restrict__ bk, const float* __restrict__ bv,
    u16* __restrict__ qb, u16* __restrict__ kb, u16* __restrict__ vtb) {
  const int p = blockIdx.y;
  const int task = blockIdx.x * 4 + (threadIdx.x >> 6);
  const int lane = threadIdx.x & 63, lr = lane & 15, lg = lane >> 4;
  const u16* xb = p == 0 ? xqb : (p == 1 ? xkb : xvb);
  const u16* wT = p == 0 ? wTq : (p == 1 ? wTk : wTv);
  const float* bias = p == 0 ? bq : (p == 1 ? bk : bv);
  const f32x4 zz = {0.f, 0.f, 0.f, 0.f};
  f32x4 acc[4] = {zz, zz, zz, zz};

  if (p < 2) {
    const int n0 = (task >> 2) * 16, c0 = (task & 3) * 64;
    const u16* ap = xb + ((size_t)n0 + lr) * D_ + lg * 8;
    const u16* bp = wT + ((size_t)c0 + lr) * D_ + lg * 8;
#pragma unroll
    for (int ks = 0; ks < 8; ++ks) {
      const short8 a = *(const short8*)(ap + ks * 32);
#pragma unroll
      for (int cg = 0; cg < 4; ++cg) {
        const short8 b = *(const short8*)(bp + (size_t)cg * 16 * D_ + ks * 32);
        acc[cg] = __builtin_amdgcn_mfma_f32_16x16x32_bf16(a, b, acc[cg], 0, 0, 0);
      }
    }
    u16* ob = p == 0 ? qb : kb;
    const float sc = p == 0 ? QSCALE : 1.0f;
    const int bidx = n0 >> 11;
    const int nn = (n0 & (N_ - 1)) + lg * 4;
#pragma unroll
    for (int cg = 0; cg < 4; ++cg) {
      const int c = c0 + cg * 16 + lr;
      const float bb = bias[c];
      const int hh = c >> 5, dd = c & 31;
      u16* op = ob + (((size_t)(bidx * H_ + hh)) * N_ + nn) * DH_ + dd;
#pragma unroll
      for (int j = 0; j < 4; ++j) op[j * DH_] = f2bf((acc[cg][j] + bb) * sc);
    }
  } else {
    const int c0 = (task & 15) * 16, n0 = (task >> 4) * 64;
    const u16* ap = wT + ((size_t)c0 + lr) * D_ + lg * 8;
    const u16* bp = xb + ((size_t)n0 + lr) * D_ + lg * 8;
#pragma unroll
    for (int ks = 0; ks < 8; ++ks) {
      const short8 a = *(const short8*)(ap + ks * 32);
#pragma unroll
      for (int ng = 0; ng < 4; ++ng) {
        const short8 b = *(const short8*)(bp + (size_t)ng * 16 * D_ + ks * 32);
        acc[ng] = __builtin_amdgcn_mfma_f32_16x16x32_bf16(a, b, acc[ng], 0, 0, 0);
      }
    }
    const int bidx = n0 >> 11, m0r = n0 & (M_ - 1);
    const int hh = c0 >> 5;
    const f32x4 bias4 = *(const f32x4*)(bias + c0 + lg * 4);
#pragma unroll
    for (int ng = 0; ng < 4; ++ng) {
#pragma unroll
      for (int j = 0; j < 4; ++j) {
        const int dd = (c0 & 31) + lg * 4 + j;
        vtb[(((size_t)(bidx * H_ + hh)) * DH_ + dd) * M_ + m0r + ng * 16 + lr] =
            f2bf(acc[ng][j] + bias4[j]);
      }
    }
  }
}

// ---------- K2: flash attention, no-max, key-split 2, block-shared KV in LDS ----------
// grid = 2 splits x 16 bh x 16 qblocks; block = 512 thr = 8 waves (16 q-rows each),
// all waves share (bh, split). Per 64-key chunk: K/V staged ONCE per block via
// global_load_lds (16B, source pre-swizzled so linear LDS = conflict-free layout),
// double-buffered with one-chunk prefetch (2-phase template). Per wave:
// S^T = mfma(K,Q); mask+exp2 (no max); P packed bf16 -> dbuf swizzled LDS;
// PV for chunk i-1 runs in iteration i (V-frags carried in regs) so the
// ds_write->ds_read round trip spans a full iteration.
__global__ __launch_bounds__(512, 4) void attn_kernel(
    const u16* __restrict__ qb, const u16* __restrict__ kb,
    const u16* __restrict__ vtb, const float* __restrict__ presence,
    float* __restrict__ opart, float* __restrict__ lpart) {
  __shared__ u16 kvlds[2][4096];    // [buf]: K[64 keys][32 d] swz | V[32 d][64 keys] swz
  __shared__ u16 plds[8][2][1024];  // per-wave dbuf P tile [16 q][64 k], swizzled
  const int tid = threadIdx.x;
  const int wv = tid >> 6, lane = tid & 63;
  const int lr = lane & 15, lg = lane >> 4;
  const int s = blockIdx.x >> 8;
  const int bh = (blockIdx.x >> 4) & 15;
  const int qblk = blockIdx.x & 15;
  const int b = bh >> 3, h = bh & 7;
  const int n0 = qblk * 128 + wv * 16;
  const int m0 = s * (M_ / 2);
  const int NI = (M_ / 2) / 64;  // 16 chunks

  // staging source (per-lane, pre-swizzled): waves 0-3 stage K, 4-7 stage V
  const u16* sptr;
  size_t sstep;
  if (wv < 4) {
    const int key = wv * 16 + (lane >> 2);
    const int gs = (lane & 3) ^ ((key >> 1) & 3);
    sptr = kb + ((size_t)bh * M_ + m0 + key) * DH_ + gs * 8;
    sstep = (size_t)64 * DH_;
  } else {
    const int d = (wv - 4) * 8 + (lane >> 3);
    const int gs = (lane & 7) ^ (d & 7);
    sptr = vtb + ((size_t)bh * DH_ + d) * M_ + m0 + gs * 8;
    sstep = 64;
  }
  u16* const ldsw = (u16*)((char*)kvlds + wv * 1024);  // wave-uniform stage dest

  // per-lane LDS fragment read offsets (u16 units)
  const int ko0 = lr * 32 + (lg ^ ((lr >> 1) & 3)) * 8;  // K: + t*512
  const int sw = lr & 7;
  const int vo0 = lr * 64 + (lg ^ sw) * 8;        // V: d=lr, keys lg*8
  const int vo1 = lr * 64 + ((4 + lg) ^ sw) * 8;  // V: d=lr, keys 32+lg*8

  // Q as B-frag of S^T: col=query=lr, k=d=lg*8+j
  const short8 qf = *(const short8*)(qb + ((size_t)bh * N_ + n0 + lr) * DH_ + lg * 8);
  const float* pbase = presence + (size_t)b * M_ + m0 + lg * 4;
  u16* const plw0 = &plds[wv][0][0] + lr * 64;
  u16* const plw1 = &plds[wv][1][0] + lr * 64;

  const f32x4 zz = {0.f, 0.f, 0.f, 0.f};
  f32x4 o0 = zz, o1 = zz, racc = zz;
  short8 vp0, vp1, vp2, vp3;

  gload_lds16(sptr, ldsw);  // chunk 0 -> buf 0
  __syncthreads();

#pragma unroll 2
  for (int i = 0; i < NI; ++i) {
    const int mm = i * 64;
    const u16* kl = &kvlds[i & 1][0];
    const u16* vl = &kvlds[i & 1][2048];
    // presence first (its vmcnt wait must not drain the stage-DMA below)
    f32x4 pr[4];
#pragma unroll
    for (int t = 0; t < 4; ++t) pr[t] = *(const f32x4*)(pbase + mm + t * 16);
    if (i + 1 < NI)
      gload_lds16(sptr + (size_t)(i + 1) * sstep, (u16*)((char*)ldsw + ((i + 1) & 1) * 8192));

    f32x4 s4[4];
#pragma unroll
    for (int t = 0; t < 4; ++t) {
      const short8 kf = *(const short8*)(kl + t * 512 + ko0);
      s4[t] = __builtin_amdgcn_mfma_f32_16x16x32_bf16(kf, qf, zz, 0, 0, 0);
    }
    const short8 v0 = *(const short8*)(vl + vo0);
    const short8 v1 = *(const short8*)(vl + vo1);
    const short8 v2 = *(const short8*)(vl + 1024 + vo0);
    const short8 v3 = *(const short8*)(vl + 1024 + vo1);

    u16* const plw = (i & 1) ? plw1 : plw0;
#pragma unroll
    for (int t = 0; t < 4; ++t) {
      s4[t] += (pr[t] - 1.f) * 1e30f;  // exact 0 present / -1e30 masked
#pragma unroll
      for (int j = 0; j < 4; ++j) s4[t][j] = EXP2(s4[t][j]);
      racc += s4[t];
      const int slot = (2 * t + (lg >> 1)) ^ sw;
      *(uint2*)(plw + slot * 8 + (lg & 1) * 4) =
          make_uint2(cvtpk_bf16(s4[t][0], s4[t][1]), cvtpk_bf16(s4[t][2], s4[t][3]));
    }
    if (i > 0) {  // PV for chunk i-1 (P in other buffer, V in carried regs)
      u16* const plr = (i & 1) ? plw0 : plw1;
      const short8 pf0 = *(const short8*)(plr + (lg ^ sw) * 8);
      const short8 pf1 = *(const short8*)(plr + ((4 + lg) ^ sw) * 8);
      o0 = __builtin_amdgcn_mfma_f32_16x16x32_bf16(pf0, vp0, o0, 0, 0, 0);
      o0 = __builtin_amdgcn_mfma_f32_16x16x32_bf16(pf1, vp1, o0, 0, 0, 0);
      o1 = __builtin_amdgcn_mfma_f32_16x16x32_bf16(pf0, vp2, o1, 0, 0, 0);
      o1 = __builtin_amdgcn_mfma_f32_16x16x32_bf16(pf1, vp3, o1, 0, 0, 0);
    }
    vp0 = v0; vp1 = v1; vp2 = v2; vp3 = v3;
    __syncthreads();
  }
  {  // epilogue: PV for chunk NI-1 (P in buf (NI-1)&1 = 1)
    u16* const plr = plw1;
    const short8 pf0 = *(const short8*)(plr + (lg ^ sw) * 8);
    const short8 pf1 = *(const short8*)(plr + ((4 + lg) ^ sw) * 8);
    o0 = __builtin_amdgcn_mfma_f32_16x16x32_bf16(pf0, vp0, o0, 0, 0, 0);
    o0 = __builtin_amdgcn_mfma_f32_16x16x32_bf16(pf1, vp1, o0, 0, 0, 0);
    o1 = __builtin_amdgcn_mfma_f32_16x16x32_bf16(pf0, vp2, o1, 0, 0, 0);
    o1 = __builtin_amdgcn_mfma_f32_16x16x32_bf16(pf1, vp3, o1, 0, 0, 0);
  }

  float l = (racc[0] + racc[1]) + (racc[2] + racc[3]);
  l += __shfl_xor(l, 16);
  l += __shfl_xor(l, 32);
  if (lg == 0) lpart[((size_t)s * (B_ * N_) + b * N_ + n0 + lr) * H_ + h] = l;

  float* ob = opart + ((size_t)s * (B_ * N_) + (size_t)b * N_ + n0) * D_ + h * DH_;
#pragma unroll
  for (int j = 0; j < 4; ++j) {
    const int q = lg * 4 + j;
    ob[(size_t)q * D_ + lr] = o0[j];
    ob[(size_t)q * D_ + 16 + lr] = o1[j];
  }
}

// ---------- K3: output projection (combine partials, normalize, bf16 MFMA) ----------
__global__ __launch_bounds__(256) void projo_kernel(
    const float* __restrict__ opart, const float* __restrict__ lpart,
    const u16* __restrict__ wTo, const float* __restrict__ bo,
    float* __restrict__ out) {
  const int task = blockIdx.x * 4 + (threadIdx.x >> 6);
  const int lane = threadIdx.x & 63, lr = lane & 15, lg = lane >> 4;
  const int n0 = (task >> 2) * 16, c0 = (task & 3) * 64;
  const float* o0p = opart + ((size_t)n0 + lr) * D_ + lg * 8;
  const float* o1p = o0p + (size_t)(B_ * N_) * D_;
  const float* l0 = lpart + ((size_t)n0 + lr) * H_;
  const float* l1 = l0 + (size_t)(B_ * N_) * H_;
  float il[8];
#pragma unroll
  for (int hh = 0; hh < 8; ++hh) il[hh] = 1.0f / (l0[hh] + l1[hh]);

  const u16* bp = wTo + ((size_t)c0 + lr) * D_ + lg * 8;
  const f32x4 zz = {0.f, 0.f, 0.f, 0.f};
  f32x4 acc[4] = {zz, zz, zz, zz};
#pragma unroll
  for (int ks = 0; ks < 8; ++ks) {
    f32x4 xa = *(const f32x4*)(o0p + ks * 32) + *(const f32x4*)(o1p + ks * 32);
    f32x4 xb = *(const f32x4*)(o0p + ks * 32 + 4) + *(const f32x4*)(o1p + ks * 32 + 4);
    const float sc = il[ks];  // head of channels ks*32+lg*8+j is ks
    xa *= sc;
    xb *= sc;
    u4s8 a;
    a.u.x = cvtpk_bf16(xa[0], xa[1]);
    a.u.y = cvtpk_bf16(xa[2], xa[3]);
    a.u.z = cvtpk_bf16(xb[0], xb[1]);
    a.u.w = cvtpk_bf16(xb[2], xb[3]);
#pragma unroll
    for (int cg = 0; cg < 4; ++cg) {
      const short8 b = *(const short8*)(bp + (size_t)cg * 16 * D_ + ks * 32);
      acc[cg] = __builtin_amdgcn_mfma_f32_16x16x32_bf16(a.s, b, acc[cg], 0, 0, 0);
    }
  }
#pragma unroll
  for (int cg = 0; cg < 4; ++cg) {
    const int c = c0 + cg * 16 + lr;
    const float bb = bo[c];
#pragma unroll
    for (int j = 0; j < 4; ++j)
      out[(size_t)(n0 + lg * 4 + j) * D_ + c] = acc[cg][j] + bb;
  }
}

extern "C" void kernel_launch(void* const* d_in, const int* in_sizes, int n_in,
                              void* d_out, int out_size, void* d_ws, size_t ws_size,
                              hipStream_t stream) {
  (void)in_sizes; (void)n_in; (void)out_size; (void)ws_size;
  const float* queries  = (const float*)d_in[0];
  const float* keys     = (const float*)d_in[1];
  const float* values   = (const float*)d_in[2];
  const float* presence = (const float*)d_in[3];
  const float* Wq = (const float*)d_in[4];
  const float* bq = (const float*)d_in[5];
  const float* Wk = (const float*)d_in[6];
  const float* bk = (const float*)d_in[7];
  const float* Wv = (const float*)d_in[8];
  const float* bv = (const float*)d_in[9];
  const float* Wo = (const float*)d_in[10];
  const float* bo = (const float*)d_in[11];

  // ws layout: wT x4 | qb | kb | vtb | {xqb,xkb,xvb overlapped by opart}+lpart
  u16* wTq = (u16*)d_ws;
  u16* wTk = wTq + 65536;
  u16* wTv = wTk + 65536;
  u16* wTo = wTv + 65536;
  u16* qb  = wTo + 65536;
  u16* kb  = qb + (size_t)B_ * H_ * N_ * DH_;
  u16* vtb = kb + (size_t)B_ * H_ * M_ * DH_;
  u16* xqb = vtb + (size_t)B_ * H_ * DH_ * M_;
  u16* xkb = xqb + (size_t)B_ * N_ * D_;
  u16* xvb = xkb + (size_t)B_ * M_ * D_;
  float* opart = (float*)xqb;  // reuses x-convert region after qkvproj consumed it
  float* lpart = opart + (size_t)2 * B_ * N_ * D_;

  conv_kernel<<<1600, 256, 0, stream>>>(queries, keys, values, Wq, Wk, Wv, Wo,
                                        xqb, xkb, xvb, wTq, wTk, wTv, wTo);
  qkvproj_kernel<<<dim3(256, 3), 256, 0, stream>>>(xqb, xkb, xvb, wTq, wTk, wTv,
                                                   bq, bk, bv, qb, kb, vtb);
  attn_kernel<<<512, 512, 0, stream>>>(qb, kb, vtb, presence, opart, lpart);
  projo_kernel<<<256, 256, 0, stream>>>(opart, lpart, wTo, bo, (float*)d_out);
}

// Round 6
// 49.374 us; speedup vs baseline: 2.5398x; 1.2072x over previous
//
#include <hip/hip_runtime.h>

#define B_ 2
#define N_ 2048
#define M_ 2048
#define D_ 256
#define H_ 8
#define DH_ 32
#define SPLITS 2
// 1/sqrt(32) * log2(e): fold into q projection; attention works in exp2 domain
#define QSCALE (0.17677669529663689f * 1.4426950408889634f)

typedef __attribute__((ext_vector_type(8))) short short8;
typedef __attribute__((ext_vector_type(4))) float f32x4;
typedef unsigned short u16;
typedef unsigned int u32;

#if __has_builtin(__builtin_amdgcn_exp2f)
#define EXP2 __builtin_amdgcn_exp2f
#else
#define EXP2 exp2f
#endif

__device__ __forceinline__ u16 f2bf(float f) {
  u32 u = __float_as_uint(f);
  return (u16)((u + 0x7fffu + ((u >> 16) & 1u)) >> 16);  // RNE
}
__device__ __forceinline__ u32 cvtpk_bf16(float lo, float hi) {
  u32 r;
  asm("v_cvt_pk_bf16_f32 %0, %1, %2" : "=v"(r) : "v"(lo), "v"(hi));
  return r;
}
__device__ __forceinline__ void gload_lds16(const u16* g, u16* l) {
  __builtin_amdgcn_global_load_lds((const __attribute__((address_space(1))) void*)g,
                                   (__attribute__((address_space(3))) void*)l, 16, 0, 0);
}

// ---------- K1: fused q/k/v projection (reads f32 X and W directly) ----------
// block = 64 c x 64 n, 4 waves. W transpose-converted to LDS bf16 (swizzled);
// X converted to LDS bf16 (swizzled). Outputs: q/k [bh][n][32] (q * QSCALE),
// v transposed [bh][32][M]  (round-4 attn interface, no presence folding).
__global__ __launch_bounds__(256, 2) void qkvproj_kernel(
    const float* __restrict__ Xq, const float* __restrict__ Xk, const float* __restrict__ Xv,
    const float* __restrict__ Wq, const float* __restrict__ Wk, const float* __restrict__ Wv,
    const float* __restrict__ bq, const float* __restrict__ bk, const float* __restrict__ bv,
    u16* __restrict__ qb, u16* __restrict__ kb, u16* __restrict__ vtb) {
  __shared__ u16 wsT[64 * 256];  // [c][k] = W[k][c], 16B-slot swizzle (k>>3)^(c&7)
  __shared__ u16 xs[64 * 256];   // [n][k] = X[n][k], swizzle (k>>3)^(n&7)
  const int p = blockIdx.y;
  const int nb = blockIdx.x & 63, cb = blockIdx.x >> 6;
  const int n0B = nb * 64, c0B = cb * 64;
  const float* X = p == 0 ? Xq : (p == 1 ? Xk : Xv);
  const float* W = p == 0 ? Wq : (p == 1 ? Wk : Wv);
  const float* bias = p == 0 ? bq : (p == 1 ? bk : bv);
  const int t = threadIdx.x;

  {  // stage W^T
    const int cL = (t & 15) * 4, kB = (t >> 4) * 16;
    const float* wp = W + (size_t)kB * D_ + c0B + cL;
#pragma unroll
    for (int u = 0; u < 4; ++u) {
      const int k0 = kB + 4 * u;
      const f32x4 w0 = *(const f32x4*)(wp + (size_t)(4 * u + 0) * D_);
      const f32x4 w1 = *(const f32x4*)(wp + (size_t)(4 * u + 1) * D_);
      const f32x4 w2 = *(const f32x4*)(wp + (size_t)(4 * u + 2) * D_);
      const f32x4 w3 = *(const f32x4*)(wp + (size_t)(4 * u + 3) * D_);
#pragma unroll
      for (int cc = 0; cc < 4; ++cc) {
        const int c = cL + cc;
        uint2 v;
        v.x = cvtpk_bf16(w0[cc], w1[cc]);
        v.y = cvtpk_bf16(w2[cc], w3[cc]);
        *(uint2*)(wsT + c * 256 + (((k0 >> 3) ^ (c & 7)) * 8) + (k0 & 7)) = v;
      }
    }
  }
  {  // stage X
    const int nL = t >> 2, k64 = (t & 3) * 64;
    const float* xp = X + (size_t)(n0B + nL) * D_ + k64;
#pragma unroll
    for (int m = 0; m < 8; ++m) {
      const f32x4 a = *(const f32x4*)(xp + 8 * m);
      const f32x4 b = *(const f32x4*)(xp + 8 * m + 4);
      uint4 v;
      v.x = cvtpk_bf16(a[0], a[1]);
      v.y = cvtpk_bf16(a[2], a[3]);
      v.z = cvtpk_bf16(b[0], b[1]);
      v.w = cvtpk_bf16(b[2], b[3]);
      const int k0 = k64 + 8 * m;
      *(uint4*)(xs + nL * 256 + (((k0 >> 3) ^ (nL & 7)) * 8)) = v;
    }
  }
  __syncthreads();

  const int wv = t >> 6, lane = t & 63, lr = lane & 15, lg = lane >> 4;
  const f32x4 zz = {0.f, 0.f, 0.f, 0.f};
  f32x4 acc[4] = {zz, zz, zz, zz};
  const int arow = wv * 16 + lr;
#pragma unroll
  for (int ks = 0; ks < 8; ++ks) {
    const short8 a = *(const short8*)(wsT + arow * 256 + (((ks * 4 + lg) ^ (arow & 7)) * 8));
#pragma unroll
    for (int ng = 0; ng < 4; ++ng) {
      const int brow = ng * 16 + lr;
      const short8 b = *(const short8*)(xs + brow * 256 + (((ks * 4 + lg) ^ (brow & 7)) * 8));
      acc[ng] = __builtin_amdgcn_mfma_f32_16x16x32_bf16(a, b, acc[ng], 0, 0, 0);
    }
  }

  // D layout: col(lr)=n, row(lg*4+j)=c
  const int cg4 = c0B + wv * 16 + lg * 4;
  const f32x4 bias4 = *(const f32x4*)(bias + cg4);
  if (p < 2) {
    u16* ob = p == 0 ? qb : kb;
    const float sc = p == 0 ? QSCALE : 1.0f;
#pragma unroll
    for (int ng = 0; ng < 4; ++ng) {
      const int n = n0B + ng * 16 + lr;
      const int b = n >> 11, nn = n & (N_ - 1);
#pragma unroll
      for (int j = 0; j < 4; ++j) {
        const int c = cg4 + j;
        ob[((size_t)(b * H_ + (c >> 5)) * N_ + nn) * DH_ + (c & 31)] =
            f2bf((acc[ng][j] + bias4[j]) * sc);
      }
    }
  } else {
#pragma unroll
    for (int ng = 0; ng < 4; ++ng) {
      const int n = n0B + ng * 16 + lr;
      const int b = n >> 11, nn = n & (M_ - 1);
#pragma unroll
      for (int j = 0; j < 4; ++j) {
        const int c = cg4 + j;
        vtb[((size_t)(b * H_ + (c >> 5)) * DH_ + (c & 31)) * M_ + nn] =
            f2bf(acc[ng][j] + bias4[j]);
      }
    }
  }
}

// ---------- K2: flash attention (round-4 verbatim: no-max, key-split 2, ----
// block-shared KV via global_load_lds, dbuf, deferred PV, additive mask) ----
__global__ __launch_bounds__(512, 4) void attn_kernel(
    const u16* __restrict__ qb, const u16* __restrict__ kb,
    const u16* __restrict__ vtb, const float* __restrict__ presence,
    float* __restrict__ opart, float* __restrict__ lpart) {
  __shared__ u16 kvlds[2][4096];    // [buf]: K[64 keys][32 d] swz | V[32 d][64 keys] swz
  __shared__ u16 plds[8][2][1024];  // per-wave dbuf P tile [16 q][64 k], swizzled
  const int tid = threadIdx.x;
  const int wv = tid >> 6, lane = tid & 63;
  const int lr = lane & 15, lg = lane >> 4;
  const int s = blockIdx.x >> 8;
  const int bh = (blockIdx.x >> 4) & 15;
  const int qblk = blockIdx.x & 15;
  const int b = bh >> 3, h = bh & 7;
  const int n0 = qblk * 128 + wv * 16;
  const int m0 = s * (M_ / SPLITS);
  const int NI = (M_ / SPLITS) / 64;  // 16 chunks

  // staging source (per-lane, pre-swizzled): waves 0-3 stage K, 4-7 stage V
  const u16* sptr;
  size_t sstep;
  if (wv < 4) {
    const int key = wv * 16 + (lane >> 2);
    const int gs = (lane & 3) ^ ((key >> 1) & 3);
    sptr = kb + ((size_t)bh * M_ + m0 + key) * DH_ + gs * 8;
    sstep = (size_t)64 * DH_;
  } else {
    const int d = (wv - 4) * 8 + (lane >> 3);
    const int gs = (lane & 7) ^ (d & 7);
    sptr = vtb + ((size_t)bh * DH_ + d) * M_ + m0 + gs * 8;
    sstep = 64;
  }
  u16* const ldsw = (u16*)((char*)kvlds + wv * 1024);  // wave-uniform stage dest

  // per-lane LDS fragment read offsets (u16 units)
  const int ko0 = lr * 32 + (lg ^ ((lr >> 1) & 3)) * 8;  // K: + t*512
  const int sw = lr & 7;
  const int vo0 = lr * 64 + (lg ^ sw) * 8;        // V: d=lr, keys lg*8
  const int vo1 = lr * 64 + ((4 + lg) ^ sw) * 8;  // V: d=lr, keys 32+lg*8

  // Q as B-frag of S^T: col=query=lr, k=d=lg*8+j
  const short8 qf = *(const short8*)(qb + ((size_t)bh * N_ + n0 + lr) * DH_ + lg * 8);
  const float* pbase = presence + (size_t)b * M_ + m0 + lg * 4;
  u16* const plw0 = &plds[wv][0][0] + lr * 64;
  u16* const plw1 = &plds[wv][1][0] + lr * 64;

  const f32x4 zz = {0.f, 0.f, 0.f, 0.f};
  f32x4 o0 = zz, o1 = zz, racc = zz;
  short8 vp0, vp1, vp2, vp3;

  gload_lds16(sptr, ldsw);  // chunk 0 -> buf 0
  __syncthreads();

#pragma unroll 2
  for (int i = 0; i < NI; ++i) {
    const int mm = i * 64;
    const u16* kl = &kvlds[i & 1][0];
    const u16* vl = &kvlds[i & 1][2048];
    // presence first (its vmcnt wait must not drain the stage-DMA below)
    f32x4 pr[4];
#pragma unroll
    for (int t = 0; t < 4; ++t) pr[t] = *(const f32x4*)(pbase + mm + t * 16);
    if (i + 1 < NI)
      gload_lds16(sptr + (size_t)(i + 1) * sstep, (u16*)((char*)ldsw + ((i + 1) & 1) * 8192));

    f32x4 s4[4];
#pragma unroll
    for (int t = 0; t < 4; ++t) {
      const short8 kf = *(const short8*)(kl + t * 512 + ko0);
      s4[t] = __builtin_amdgcn_mfma_f32_16x16x32_bf16(kf, qf, zz, 0, 0, 0);
    }
    const short8 v0 = *(const short8*)(vl + vo0);
    const short8 v1 = *(const short8*)(vl + vo1);
    const short8 v2 = *(const short8*)(vl + 1024 + vo0);
    const short8 v3 = *(const short8*)(vl + 1024 + vo1);

    u16* const plw = (i & 1) ? plw1 : plw0;
#pragma unroll
    for (int t = 0; t < 4; ++t) {
      s4[t] += (pr[t] - 1.f) * 1e30f;  // exact 0 present / -1e30 masked
#pragma unroll
      for (int j = 0; j < 4; ++j) s4[t][j] = EXP2(s4[t][j]);
      racc += s4[t];
      const int slot = (2 * t + (lg >> 1)) ^ sw;
      *(uint2*)(plw + slot * 8 + (lg & 1) * 4) =
          make_uint2(cvtpk_bf16(s4[t][0], s4[t][1]), cvtpk_bf16(s4[t][2], s4[t][3]));
    }
    if (i > 0) {  // PV for chunk i-1 (P in other buffer, V in carried regs)
      u16* const plr = (i & 1) ? plw0 : plw1;
      const short8 pf0 = *(const short8*)(plr + (lg ^ sw) * 8);
      const short8 pf1 = *(const short8*)(plr + ((4 + lg) ^ sw) * 8);
      o0 = __builtin_amdgcn_mfma_f32_16x16x32_bf16(pf0, vp0, o0, 0, 0, 0);
      o0 = __builtin_amdgcn_mfma_f32_16x16x32_bf16(pf1, vp1, o0, 0, 0, 0);
      o1 = __builtin_amdgcn_mfma_f32_16x16x32_bf16(pf0, vp2, o1, 0, 0, 0);
      o1 = __builtin_amdgcn_mfma_f32_16x16x32_bf16(pf1, vp3, o1, 0, 0, 0);
    }
    vp0 = v0; vp1 = v1; vp2 = v2; vp3 = v3;
    __syncthreads();
  }
  {  // epilogue: PV for chunk NI-1 (P in buf (NI-1)&1 = 1)
    u16* const plr = plw1;
    const short8 pf0 = *(const short8*)(plr + (lg ^ sw) * 8);
    const short8 pf1 = *(const short8*)(plr + ((4 + lg) ^ sw) * 8);
    o0 = __builtin_amdgcn_mfma_f32_16x16x32_bf16(pf0, vp0, o0, 0, 0, 0);
    o0 = __builtin_amdgcn_mfma_f32_16x16x32_bf16(pf1, vp1, o0, 0, 0, 0);
    o1 = __builtin_amdgcn_mfma_f32_16x16x32_bf16(pf0, vp2, o1, 0, 0, 0);
    o1 = __builtin_amdgcn_mfma_f32_16x16x32_bf16(pf1, vp3, o1, 0, 0, 0);
  }

  float l = (racc[0] + racc[1]) + (racc[2] + racc[3]);
  l += __shfl_xor(l, 16);
  l += __shfl_xor(l, 32);
  if (lg == 0) lpart[((size_t)s * (B_ * N_) + b * N_ + n0 + lr) * H_ + h] = l;

  float* ob = opart + ((size_t)s * (B_ * N_) + (size_t)b * N_ + n0) * D_ + h * DH_;
#pragma unroll
  for (int j = 0; j < 4; ++j) {
    const int q = lg * 4 + j;
    ob[(size_t)q * D_ + lr] = o0[j];
    ob[(size_t)q * D_ + 16 + lr] = o1[j];
  }
}

// ---------- K3: output projection (combine splits, normalize, MFMA) ----------
__global__ __launch_bounds__(256, 2) void projo_kernel(
    const float* __restrict__ opart, const float* __restrict__ lpart,
    const float* __restrict__ Wo, const float* __restrict__ bo,
    float* __restrict__ out) {
  __shared__ u16 wsT[64 * 256];  // Wo^T [c][k] swizzled
  __shared__ u16 xs[64 * 256];   // normalized attention output [n][k] swizzled
  const int nb = blockIdx.x & 63, cb = blockIdx.x >> 6;
  const int n0B = nb * 64, c0B = cb * 64;
  const int t = threadIdx.x;

  {  // stage Wo^T
    const int cL = (t & 15) * 4, kB = (t >> 4) * 16;
    const float* wp = Wo + (size_t)kB * D_ + c0B + cL;
#pragma unroll
    for (int u = 0; u < 4; ++u) {
      const int k0 = kB + 4 * u;
      const f32x4 w0 = *(const f32x4*)(wp + (size_t)(4 * u + 0) * D_);
      const f32x4 w1 = *(const f32x4*)(wp + (size_t)(4 * u + 1) * D_);
      const f32x4 w2 = *(const f32x4*)(wp + (size_t)(4 * u + 2) * D_);
      const f32x4 w3 = *(const f32x4*)(wp + (size_t)(4 * u + 3) * D_);
#pragma unroll
      for (int cc = 0; cc < 4; ++cc) {
        const int c = cL + cc;
        uint2 v;
        v.x = cvtpk_bf16(w0[cc], w1[cc]);
        v.y = cvtpk_bf16(w2[cc], w3[cc]);
        *(uint2*)(wsT + c * 256 + (((k0 >> 3) ^ (c & 7)) * 8) + (k0 & 7)) = v;
      }
    }
  }
  {  // stage A = (opart0 + opart1) * (1/l), bf16 swizzled
    const int nL = t >> 2, k64 = (t & 3) * 64;
    const int gn = n0B + nL;
    const float* o0p = opart + (size_t)gn * D_ + k64;
    const float* o1p = o0p + (size_t)(B_ * N_) * D_;
    const int h0 = k64 >> 5;
    const float il0 = 1.f / (lpart[(size_t)gn * H_ + h0] +
                             lpart[((size_t)(B_ * N_) + gn) * H_ + h0]);
    const float il1 = 1.f / (lpart[(size_t)gn * H_ + h0 + 1] +
                             lpart[((size_t)(B_ * N_) + gn) * H_ + h0 + 1]);
#pragma unroll
    for (int m = 0; m < 8; ++m) {
      f32x4 a = *(const f32x4*)(o0p + 8 * m) + *(const f32x4*)(o1p + 8 * m);
      f32x4 b = *(const f32x4*)(o0p + 8 * m + 4) + *(const f32x4*)(o1p + 8 * m + 4);
      const float il = (m < 4) ? il0 : il1;
      a *= il;
      b *= il;
      uint4 v;
      v.x = cvtpk_bf16(a[0], a[1]);
      v.y = cvtpk_bf16(a[2], a[3]);
      v.z = cvtpk_bf16(b[0], b[1]);
      v.w = cvtpk_bf16(b[2], b[3]);
      const int k0 = k64 + 8 * m;
      *(uint4*)(xs + nL * 256 + (((k0 >> 3) ^ (nL & 7)) * 8)) = v;
    }
  }
  __syncthreads();

  const int wv = t >> 6, lane = t & 63, lr = lane & 15, lg = lane >> 4;
  const f32x4 zz = {0.f, 0.f, 0.f, 0.f};
  f32x4 acc[4] = {zz, zz, zz, zz};
  const int arow = wv * 16 + lr;
#pragma unroll
  for (int ks = 0; ks < 8; ++ks) {
    const short8 a = *(const short8*)(xs + arow * 256 + (((ks * 4 + lg) ^ (arow & 7)) * 8));
#pragma unroll
    for (int ng = 0; ng < 4; ++ng) {
      const int brow = ng * 16 + lr;
      const short8 bfr = *(const short8*)(wsT + brow * 256 + (((ks * 4 + lg) ^ (brow & 7)) * 8));
      acc[ng] = __builtin_amdgcn_mfma_f32_16x16x32_bf16(a, bfr, acc[ng], 0, 0, 0);
    }
  }
  // D layout: col(lr)=c, row(lg*4+j)=n -> coalesced f32 stores
#pragma unroll
  for (int ng = 0; ng < 4; ++ng) {
    const int c = c0B + ng * 16 + lr;
    const float bb = bo[c];
#pragma unroll
    for (int j = 0; j < 4; ++j)
      out[(size_t)(n0B + wv * 16 + lg * 4 + j) * D_ + c] = acc[ng][j] + bb;
  }
}

extern "C" void kernel_launch(void* const* d_in, const int* in_sizes, int n_in,
                              void* d_out, int out_size, void* d_ws, size_t ws_size,
                              hipStream_t stream) {
  (void)in_sizes; (void)n_in; (void)out_size; (void)ws_size;
  const float* queries  = (const float*)d_in[0];
  const float* keys     = (const float*)d_in[1];
  const float* values   = (const float*)d_in[2];
  const float* presence = (const float*)d_in[3];
  const float* Wq = (const float*)d_in[4];
  const float* bq = (const float*)d_in[5];
  const float* Wk = (const float*)d_in[6];
  const float* bk = (const float*)d_in[7];
  const float* Wv = (const float*)d_in[8];
  const float* bv = (const float*)d_in[9];
  const float* Wo = (const float*)d_in[10];
  const float* bo = (const float*)d_in[11];

  // ws: qb 2MB | kb 2MB | vtb 2MB | opart 8MB | lpart 256KB = 14.25MB
  u16* qb  = (u16*)d_ws;
  u16* kb  = qb + (size_t)B_ * H_ * N_ * DH_;
  u16* vtb = kb + (size_t)B_ * H_ * M_ * DH_;
  float* opart = (float*)(vtb + (size_t)B_ * H_ * DH_ * M_);
  float* lpart = opart + (size_t)SPLITS * B_ * N_ * D_;

  qkvproj_kernel<<<dim3(256, 3), 256, 0, stream>>>(
      queries, keys, values, Wq, Wk, Wv, bq, bk, bv, qb, kb, vtb);
  attn_kernel<<<SPLITS * 16 * 16, 512, 0, stream>>>(qb, kb, vtb, presence, opart, lpart);
  projo_kernel<<<256, 256, 0, stream>>>(opart, lpart, Wo, bo, (float*)d_out);
}

// Round 7
// 47.571 us; speedup vs baseline: 2.6361x; 1.0379x over previous
//
#include <hip/hip_runtime.h>

#define B_ 2
#define N_ 2048
#define M_ 2048
#define D_ 256
#define H_ 8
#define DH_ 32
#define SPLITS 2
// 1/sqrt(32) * log2(e): fold into q projection; attention works in exp2 domain
#define QSCALE (0.17677669529663689f * 1.4426950408889634f)

typedef __attribute__((ext_vector_type(8))) short short8;
typedef __attribute__((ext_vector_type(4))) float f32x4;
typedef unsigned short u16;
typedef unsigned int u32;

#if __has_builtin(__builtin_amdgcn_exp2f)
#define EXP2 __builtin_amdgcn_exp2f
#else
#define EXP2 exp2f
#endif

__device__ __forceinline__ u16 f2bf(float f) {
  u32 u = __float_as_uint(f);
  return (u16)((u + 0x7fffu + ((u >> 16) & 1u)) >> 16);  // RNE
}
__device__ __forceinline__ u32 cvtpk_bf16(float lo, float hi) {
  u32 r;
  asm("v_cvt_pk_bf16_f32 %0, %1, %2" : "=v"(r) : "v"(lo), "v"(hi));
  return r;
}
__device__ __forceinline__ void gload_lds16(const u16* g, u16* l) {
  __builtin_amdgcn_global_load_lds((const __attribute__((address_space(1))) void*)g,
                                   (__attribute__((address_space(3))) void*)l, 16, 0, 0);
}

// ---------- K1: fused q/k/v projection (reads f32 X and W directly) ----------
// block = 64 c x 64 n, 4 waves. W transpose-converted to LDS bf16 (swizzled);
// X converted to LDS bf16 (swizzled). Outputs: q/k [bh][n][32] (q * QSCALE),
// v transposed [bh][32][M].
__global__ __launch_bounds__(256, 2) void qkvproj_kernel(
    const float* __restrict__ Xq, const float* __restrict__ Xk, const float* __restrict__ Xv,
    const float* __restrict__ Wq, const float* __restrict__ Wk, const float* __restrict__ Wv,
    const float* __restrict__ bq, const float* __restrict__ bk, const float* __restrict__ bv,
    u16* __restrict__ qb, u16* __restrict__ kb, u16* __restrict__ vtb) {
  __shared__ u16 wsT[64 * 256];  // [c][k] = W[k][c], 16B-slot swizzle (k>>3)^(c&7)
  __shared__ u16 xs[64 * 256];   // [n][k] = X[n][k], swizzle (k>>3)^(n&7)
  const int p = blockIdx.y;
  const int nb = blockIdx.x & 63, cb = blockIdx.x >> 6;
  const int n0B = nb * 64, c0B = cb * 64;
  const float* X = p == 0 ? Xq : (p == 1 ? Xk : Xv);
  const float* W = p == 0 ? Wq : (p == 1 ? Wk : Wv);
  const float* bias = p == 0 ? bq : (p == 1 ? bk : bv);
  const int t = threadIdx.x;

  {  // stage W^T
    const int cL = (t & 15) * 4, kB = (t >> 4) * 16;
    const float* wp = W + (size_t)kB * D_ + c0B + cL;
#pragma unroll
    for (int u = 0; u < 4; ++u) {
      const int k0 = kB + 4 * u;
      const f32x4 w0 = *(const f32x4*)(wp + (size_t)(4 * u + 0) * D_);
      const f32x4 w1 = *(const f32x4*)(wp + (size_t)(4 * u + 1) * D_);
      const f32x4 w2 = *(const f32x4*)(wp + (size_t)(4 * u + 2) * D_);
      const f32x4 w3 = *(const f32x4*)(wp + (size_t)(4 * u + 3) * D_);
#pragma unroll
      for (int cc = 0; cc < 4; ++cc) {
        const int c = cL + cc;
        uint2 v;
        v.x = cvtpk_bf16(w0[cc], w1[cc]);
        v.y = cvtpk_bf16(w2[cc], w3[cc]);
        *(uint2*)(wsT + c * 256 + (((k0 >> 3) ^ (c & 7)) * 8) + (k0 & 7)) = v;
      }
    }
  }
  {  // stage X
    const int nL = t >> 2, k64 = (t & 3) * 64;
    const float* xp = X + (size_t)(n0B + nL) * D_ + k64;
#pragma unroll
    for (int m = 0; m < 8; ++m) {
      const f32x4 a = *(const f32x4*)(xp + 8 * m);
      const f32x4 b = *(const f32x4*)(xp + 8 * m + 4);
      uint4 v;
      v.x = cvtpk_bf16(a[0], a[1]);
      v.y = cvtpk_bf16(a[2], a[3]);
      v.z = cvtpk_bf16(b[0], b[1]);
      v.w = cvtpk_bf16(b[2], b[3]);
      const int k0 = k64 + 8 * m;
      *(uint4*)(xs + nL * 256 + (((k0 >> 3) ^ (nL & 7)) * 8)) = v;
    }
  }
  __syncthreads();

  const int wv = t >> 6, lane = t & 63, lr = lane & 15, lg = lane >> 4;
  const f32x4 zz = {0.f, 0.f, 0.f, 0.f};
  f32x4 acc[4] = {zz, zz, zz, zz};
  const int arow = wv * 16 + lr;
#pragma unroll
  for (int ks = 0; ks < 8; ++ks) {
    const short8 a = *(const short8*)(wsT + arow * 256 + (((ks * 4 + lg) ^ (arow & 7)) * 8));
#pragma unroll
    for (int ng = 0; ng < 4; ++ng) {
      const int brow = ng * 16 + lr;
      const short8 b = *(const short8*)(xs + brow * 256 + (((ks * 4 + lg) ^ (brow & 7)) * 8));
      acc[ng] = __builtin_amdgcn_mfma_f32_16x16x32_bf16(a, b, acc[ng], 0, 0, 0);
    }
  }

  // D layout: col(lr)=n, row(lg*4+j)=c
  const int cg4 = c0B + wv * 16 + lg * 4;
  const f32x4 bias4 = *(const f32x4*)(bias + cg4);
  if (p < 2) {
    u16* ob = p == 0 ? qb : kb;
    const float sc = p == 0 ? QSCALE : 1.0f;
#pragma unroll
    for (int ng = 0; ng < 4; ++ng) {
      const int n = n0B + ng * 16 + lr;
      const int b = n >> 11, nn = n & (N_ - 1);
#pragma unroll
      for (int j = 0; j < 4; ++j) {
        const int c = cg4 + j;
        ob[((size_t)(b * H_ + (c >> 5)) * N_ + nn) * DH_ + (c & 31)] =
            f2bf((acc[ng][j] + bias4[j]) * sc);
      }
    }
  } else {
#pragma unroll
    for (int ng = 0; ng < 4; ++ng) {
      const int n = n0B + ng * 16 + lr;
      const int b = n >> 11, nn = n & (M_ - 1);
#pragma unroll
      for (int j = 0; j < 4; ++j) {
        const int c = cg4 + j;
        vtb[((size_t)(b * H_ + (c >> 5)) * DH_ + (c & 31)) * M_ + nn] =
            f2bf(acc[ng][j] + bias4[j]);
      }
    }
  }
}

// ---------- K2: flash attention (no-max, key-split 2) ----------
// grid = 2 splits x 16 bh x 32 qtiles = 1024 blocks (exactly 4/CU);
// block = 256 thr = 4 waves, 16 q-rows each. Per 64-key chunk: K/V staged once
// per block via global_load_lds (pre-swizzled source, dbuf, one-chunk prefetch);
// S^T = mfma(K,Q); mask+exp2 (no max); P -> bf16 -> wave-private single-buffer
// swizzled LDS; immediate PV (wave-private RAW, lgkmcnt-ordered). setprio
// around MFMA clusters (T5).
__global__ __launch_bounds__(256, 4) void attn_kernel(
    const u16* __restrict__ qb, const u16* __restrict__ kb,
    const u16* __restrict__ vtb, const float* __restrict__ presence,
    float* __restrict__ opart, float* __restrict__ lpart) {
  __shared__ u16 kvlds[2][4096];  // [buf]: K[64 keys][32 d] swz | V[32 d][64 keys] swz
  __shared__ u16 plds[4][1024];   // per-wave P tile [16 q][64 k], swizzled
  const int t = threadIdx.x;
  const int wv = t >> 6, lane = t & 63;
  const int lr = lane & 15, lg = lane >> 4;
  const int s = blockIdx.x >> 9;
  const int bh = (blockIdx.x >> 5) & 15;
  const int qblk = blockIdx.x & 31;
  const int b = bh >> 3, h = bh & 7;
  const int n0 = qblk * 64 + wv * 16;
  const int m0 = s * (M_ / SPLITS);
  const int NI = (M_ / SPLITS) / 64;  // 16 chunks

  // staging sources (per-lane, pre-swizzled). Each thread: one 16B K piece
  // (key = t>>2, slot t&3, swz (key>>1)&3) and one 16B V piece (d = t>>3,
  // slot t&7, swz d&7). LDS positions identical to round-6 layout.
  const int gsk = (t & 3) ^ ((t >> 3) & 3);
  const u16* kst = kb + ((size_t)bh * M_ + m0 + (t >> 2)) * DH_ + gsk * 8;
  const int gsv = (t & 7) ^ ((t >> 3) & 7);
  const u16* vst = vtb + ((size_t)bh * DH_ + (t >> 3)) * M_ + m0 + gsv * 8;
  u16* const ldswK = &kvlds[0][0] + wv * 512;         // + buf*4096
  u16* const ldswV = &kvlds[0][0] + 2048 + wv * 512;  // + buf*4096

  // per-lane LDS fragment read offsets (u16 units)
  const int ko0 = lr * 32 + (lg ^ ((lr >> 1) & 3)) * 8;  // K: + tt*512
  const int sw = lr & 7;
  const int vo0 = (lg ^ sw) * 8;        // keys lg*8
  const int vo1 = ((4 + lg) ^ sw) * 8;  // keys 32+lg*8

  // Q as B-frag of S^T: col=query=lr, k=d=lg*8+j
  const short8 qf = *(const short8*)(qb + ((size_t)bh * N_ + n0 + lr) * DH_ + lg * 8);
  const float* pbase = presence + (size_t)b * M_ + m0 + lg * 4;
  u16* const plw = plds[wv] + lr * 64;

  const f32x4 zz = {0.f, 0.f, 0.f, 0.f};
  f32x4 o0 = zz, o1 = zz, racc = zz;

  gload_lds16(kst, ldswK);  // chunk 0 -> buf 0
  gload_lds16(vst, ldswV);
  __syncthreads();

#pragma unroll 2
  for (int i = 0; i < NI; ++i) {
    const int mm = i * 64;
    const u16* kl = &kvlds[i & 1][0];
    const u16* vl = &kvlds[i & 1][2048];
    // presence first (its vmcnt wait must not drain the stage-DMA below)
    f32x4 pr[4];
#pragma unroll
    for (int tt = 0; tt < 4; ++tt) pr[tt] = *(const f32x4*)(pbase + mm + tt * 16);
    if (i + 1 < NI) {  // prefetch chunk i+1 into other buffer
      const int bo = ((i + 1) & 1) * 4096;
      gload_lds16(kst + (size_t)(i + 1) * (64 * DH_), ldswK + bo);
      gload_lds16(vst + (size_t)(i + 1) * 64, ldswV + bo);
    }

    f32x4 s4[4];
    __builtin_amdgcn_s_setprio(1);
#pragma unroll
    for (int tt = 0; tt < 4; ++tt) {
      const short8 kf = *(const short8*)(kl + tt * 512 + ko0);
      s4[tt] = __builtin_amdgcn_mfma_f32_16x16x32_bf16(kf, qf, zz, 0, 0, 0);
    }
    __builtin_amdgcn_s_setprio(0);

#pragma unroll
    for (int tt = 0; tt < 4; ++tt) {
      s4[tt] += (pr[tt] - 1.f) * 1e30f;  // exact 0 present / -1e30 masked
#pragma unroll
      for (int j = 0; j < 4; ++j) s4[tt][j] = EXP2(s4[tt][j]);
      racc += s4[tt];
      const int slot = (2 * tt + (lg >> 1)) ^ sw;
      *(uint2*)(plw + slot * 8 + (lg & 1) * 4) =
          make_uint2(cvtpk_bf16(s4[tt][0], s4[tt][1]), cvtpk_bf16(s4[tt][2], s4[tt][3]));
    }
    // immediate PV (wave-private P tile; compiler orders via lgkmcnt)
    const short8 pf0 = *(const short8*)(plw + vo0);
    const short8 pf1 = *(const short8*)(plw + vo1);
    const short8 vf0 = *(const short8*)(vl + lr * 64 + vo0);
    const short8 vf1 = *(const short8*)(vl + lr * 64 + vo1);
    const short8 vf2 = *(const short8*)(vl + (16 + lr) * 64 + vo0);
    const short8 vf3 = *(const short8*)(vl + (16 + lr) * 64 + vo1);
    __builtin_amdgcn_s_setprio(1);
    o0 = __builtin_amdgcn_mfma_f32_16x16x32_bf16(pf0, vf0, o0, 0, 0, 0);
    o0 = __builtin_amdgcn_mfma_f32_16x16x32_bf16(pf1, vf1, o0, 0, 0, 0);
    o1 = __builtin_amdgcn_mfma_f32_16x16x32_bf16(pf0, vf2, o1, 0, 0, 0);
    o1 = __builtin_amdgcn_mfma_f32_16x16x32_bf16(pf1, vf3, o1, 0, 0, 0);
    __builtin_amdgcn_s_setprio(0);
    __syncthreads();
  }

  float l = (racc[0] + racc[1]) + (racc[2] + racc[3]);
  l += __shfl_xor(l, 16);
  l += __shfl_xor(l, 32);
  if (lg == 0) lpart[((size_t)s * (B_ * N_) + b * N_ + n0 + lr) * H_ + h] = l;

  float* ob = opart + ((size_t)s * (B_ * N_) + (size_t)b * N_ + n0) * D_ + h * DH_;
#pragma unroll
  for (int j = 0; j < 4; ++j) {
    const int q = lg * 4 + j;
    ob[(size_t)q * D_ + lr] = o0[j];
    ob[(size_t)q * D_ + 16 + lr] = o1[j];
  }
}

// ---------- K3: output projection (combine splits, normalize, MFMA) ----------
__global__ __launch_bounds__(256, 2) void projo_kernel(
    const float* __restrict__ opart, const float* __restrict__ lpart,
    const float* __restrict__ Wo, const float* __restrict__ bo,
    float* __restrict__ out) {
  __shared__ u16 wsT[64 * 256];  // Wo^T [c][k] swizzled
  __shared__ u16 xs[64 * 256];   // normalized attention output [n][k] swizzled
  const int nb = blockIdx.x & 63, cb = blockIdx.x >> 6;
  const int n0B = nb * 64, c0B = cb * 64;
  const int t = threadIdx.x;

  {  // stage Wo^T
    const int cL = (t & 15) * 4, kB = (t >> 4) * 16;
    const float* wp = Wo + (size_t)kB * D_ + c0B + cL;
#pragma unroll
    for (int u = 0; u < 4; ++u) {
      const int k0 = kB + 4 * u;
      const f32x4 w0 = *(const f32x4*)(wp + (size_t)(4 * u + 0) * D_);
      const f32x4 w1 = *(const f32x4*)(wp + (size_t)(4 * u + 1) * D_);
      const f32x4 w2 = *(const f32x4*)(wp + (size_t)(4 * u + 2) * D_);
      const f32x4 w3 = *(const f32x4*)(wp + (size_t)(4 * u + 3) * D_);
#pragma unroll
      for (int cc = 0; cc < 4; ++cc) {
        const int c = cL + cc;
        uint2 v;
        v.x = cvtpk_bf16(w0[cc], w1[cc]);
        v.y = cvtpk_bf16(w2[cc], w3[cc]);
        *(uint2*)(wsT + c * 256 + (((k0 >> 3) ^ (c & 7)) * 8) + (k0 & 7)) = v;
      }
    }
  }
  {  // stage A = (opart0 + opart1) * (1/l), bf16 swizzled
    const int nL = t >> 2, k64 = (t & 3) * 64;
    const int gn = n0B + nL;
    const float* o0p = opart + (size_t)gn * D_ + k64;
    const float* o1p = o0p + (size_t)(B_ * N_) * D_;
    const int h0 = k64 >> 5;
    const float il0 = 1.f / (lpart[(size_t)gn * H_ + h0] +
                             lpart[((size_t)(B_ * N_) + gn) * H_ + h0]);
    const float il1 = 1.f / (lpart[(size_t)gn * H_ + h0 + 1] +
                             lpart[((size_t)(B_ * N_) + gn) * H_ + h0 + 1]);
#pragma unroll
    for (int m = 0; m < 8; ++m) {
      f32x4 a = *(const f32x4*)(o0p + 8 * m) + *(const f32x4*)(o1p + 8 * m);
      f32x4 b = *(const f32x4*)(o0p + 8 * m + 4) + *(const f32x4*)(o1p + 8 * m + 4);
      const float il = (m < 4) ? il0 : il1;
      a *= il;
      b *= il;
      uint4 v;
      v.x = cvtpk_bf16(a[0], a[1]);
      v.y = cvtpk_bf16(a[2], a[3]);
      v.z = cvtpk_bf16(b[0], b[1]);
      v.w = cvtpk_bf16(b[2], b[3]);
      const int k0 = k64 + 8 * m;
      *(uint4*)(xs + nL * 256 + (((k0 >> 3) ^ (nL & 7)) * 8)) = v;
    }
  }
  __syncthreads();

  const int wv = t >> 6, lane = t & 63, lr = lane & 15, lg = lane >> 4;
  const f32x4 zz = {0.f, 0.f, 0.f, 0.f};
  f32x4 acc[4] = {zz, zz, zz, zz};
  const int arow = wv * 16 + lr;
#pragma unroll
  for (int ks = 0; ks < 8; ++ks) {
    const short8 a = *(const short8*)(xs + arow * 256 + (((ks * 4 + lg) ^ (arow & 7)) * 8));
#pragma unroll
    for (int ng = 0; ng < 4; ++ng) {
      const int brow = ng * 16 + lr;
      const short8 bfr = *(const short8*)(wsT + brow * 256 + (((ks * 4 + lg) ^ (brow & 7)) * 8));
      acc[ng] = __builtin_amdgcn_mfma_f32_16x16x32_bf16(a, bfr, acc[ng], 0, 0, 0);
    }
  }
  // D layout: col(lr)=c, row(lg*4+j)=n -> coalesced f32 stores
#pragma unroll
  for (int ng = 0; ng < 4; ++ng) {
    const int c = c0B + ng * 16 + lr;
    const float bb = bo[c];
#pragma unroll
    for (int j = 0; j < 4; ++j)
      out[(size_t)(n0B + wv * 16 + lg * 4 + j) * D_ + c] = acc[ng][j] + bb;
  }
}

extern "C" void kernel_launch(void* const* d_in, const int* in_sizes, int n_in,
                              void* d_out, int out_size, void* d_ws, size_t ws_size,
                              hipStream_t stream) {
  (void)in_sizes; (void)n_in; (void)out_size; (void)ws_size;
  const float* queries  = (const float*)d_in[0];
  const float* keys     = (const float*)d_in[1];
  const float* values   = (const float*)d_in[2];
  const float* presence = (const float*)d_in[3];
  const float* Wq = (const float*)d_in[4];
  const float* bq = (const float*)d_in[5];
  const float* Wk = (const float*)d_in[6];
  const float* bk = (const float*)d_in[7];
  const float* Wv = (const float*)d_in[8];
  const float* bv = (const float*)d_in[9];
  const float* Wo = (const float*)d_in[10];
  const float* bo = (const float*)d_in[11];

  // ws: qb 2MB | kb 2MB | vtb 2MB | opart 8MB | lpart 256KB = 14.25MB
  u16* qb  = (u16*)d_ws;
  u16* kb  = qb + (size_t)B_ * H_ * N_ * DH_;
  u16* vtb = kb + (size_t)B_ * H_ * M_ * DH_;
  float* opart = (float*)(vtb + (size_t)B_ * H_ * DH_ * M_);
  float* lpart = opart + (size_t)SPLITS * B_ * N_ * D_;

  qkvproj_kernel<<<dim3(256, 3), 256, 0, stream>>>(
      queries, keys, values, Wq, Wk, Wv, bq, bk, bv, qb, kb, vtb);
  attn_kernel<<<SPLITS * 16 * 32, 256, 0, stream>>>(qb, kb, vtb, presence, opart, lpart);
  projo_kernel<<<256, 256, 0, stream>>>(opart, lpart, Wo, bo, (float*)d_out);
}